// Round 1
// baseline (430.138 us; speedup 1.0000x reference)
//
#include <hip/hip_runtime.h>
#include <hip/hip_cooperative_groups.h>

namespace cg = cooperative_groups;

// EmbeddingCRF: feats = emb[sentence] @ W^T; CRF forward (LSE), gold score,
// Viterbi decode. Parallel-in-time via 12x12 semiring transfer matrices.
// R4: 4-level scan tree — 2048 chunks(16) -> 128 supers -> 8 hypers -> seq 8.
// R5: dispatch-count collapse. Evidence: top-5 rocprof dispatches are all the
// harness's 480MB ws-poison fills (~73us); our kernels sum to ~30us by
// roofline, so dur_us is dominated by per-dispatch overhead. 10 dispatches ->
// 2: k_feats (kept standalone for gather TLP, now writes per-block gold
// partials: memset dispatch eliminated) + one cooperative mega-kernel
// (256x256) running pass1->fold1->fold2+goldsum->mid->expandA->expandB->decode
// with 6 grid.sync()s. Fallback to the old 8-kernel chain if coop launch
// is rejected.

#define LSEQ    32768
#define NTAGS   14
#define R       12
#define T_START 12
#define T_STOP  13
#define EMBD    300
#define CCH     2048  // chunks
#define SCH     16    // steps per chunk
#define NSUP    128   // supers (16 chunks each)
#define NHYP    8     // hypers (16 supers each)

// ws layout (float offsets)
#define OFF_FEATS 0         // [L][12]
#define OFF_EXPF  393216    // [L][12]
#define OFF_FMAX  786432    // [L]
#define OFF_PF    819200    // [2048][n][p] LSE chunk mats (log domain)
#define OFF_PV    1114112   // [2048][n][p] max-plus chunk mats
#define OFF_PVC   1409024   // [2048][p][n] transposed
#define OFF_BV    1703936   // [2048][12] viterbi entry vectors
#define OFF_SFX   1728512   // [2048][12] viterbi suffix vectors
#define OFF_GOLD  1753088   // [1]
#define OFF_SMV   1753104   // [128][n][p]
#define OFF_SMVT  1771536   // [128][p][n]
#define OFF_SMF   1789968   // [128][n][p]
#define OFF_HMV   1808400   // [8][n][p]
#define OFF_HMVT  1809552   // [8][p][n]
#define OFF_HMF   1810704   // [8][n][p]
#define OFF_SBV   1811856   // [128][12]
#define OFF_SSFX  1813392   // [128][12]
#define OFF_HBV   1814928   // [8][12]
#define OFF_HSFX  1815024   // [8][12]
#define OFF_GOLDP 1815120   // [2048] per-block gold partials (appended: no
                            // off-end prefetch pattern lands here)

__device__ __forceinline__ void load12(const float* __restrict__ p, float* r) {
  const float4* p4 = (const float4*)p;
  float4 a = p4[0], b = p4[1], c = p4[2];
  r[0]=a.x; r[1]=a.y; r[2]=a.z; r[3]=a.w;
  r[4]=b.x; r[5]=b.y; r[6]=b.z; r[7]=b.w;
  r[8]=c.x; r[9]=c.y; r[10]=c.z; r[11]=c.w;
}

__device__ __forceinline__ void lds12(const float* p, float* r) {
  const float4* p4 = (const float4*)p;
  float4 a = p4[0], b = p4[1], c = p4[2];
  r[0]=a.x; r[1]=a.y; r[2]=a.z; r[3]=a.w;
  r[4]=b.x; r[5]=b.y; r[6]=b.z; r[7]=b.w;
  r[8]=c.x; r[9]=c.y; r[10]=c.z; r[11]=c.w;
}

// ---------------- K1: feats + expfeat + featmax + gold partials -------------
__global__ __launch_bounds__(256) void k_feats(
    const int* __restrict__ sentence, const int* __restrict__ tags,
    const float* __restrict__ emb, const float* __restrict__ W,
    const float* __restrict__ trans, float* __restrict__ ws)
{
  __shared__ float Wl[NTAGS * EMBD];
  __shared__ float gacc;
  for (int i = threadIdx.x; i < NTAGS * EMBD; i += 256) Wl[i] = W[i];
  if (threadIdx.x == 0) gacc = 0.f;
  __syncthreads();

  int grp = threadIdx.x >> 4;
  int g   = threadIdx.x & 15;
  int pos = blockIdx.x * 16 + grp;
  int row = sentence[pos];

  float acc = 0.f;
  if (g < R) {
    const float4* e4 = (const float4*)(emb + (size_t)row * EMBD);
    const float4* w4 = (const float4*)(Wl + g * EMBD);
    #pragma unroll 5
    for (int i = 0; i < EMBD / 4; ++i) {
      float4 a = e4[i]; float4 b = w4[i];
      acc += a.x*b.x + a.y*b.y + a.z*b.z + a.w*b.w;
    }
  }
  float feat = (g < R) ? acc : -3.0e38f;
  float mx = feat;
  #pragma unroll
  for (int off = 1; off < 16; off <<= 1)
    mx = fmaxf(mx, __shfl_xor(mx, off, 16));

  if (g < R) {
    ws[OFF_FEATS + pos * 12 + g] = feat;
    ws[OFF_EXPF  + pos * 12 + g] = __expf(feat - mx);
  }
  if (g == 0) ws[OFF_FMAX + pos] = mx;

  int tg = tags[pos];
  if (g == tg) {
    int prev = (pos == 0) ? T_START : tags[pos - 1];
    float gc = feat + trans[tg * NTAGS + prev];
    if (pos == LSEQ - 1) gc += trans[T_STOP * NTAGS + tg];
    atomicAdd(&gacc, gc);
  }
  __syncthreads();
  // per-block partial; summed inside k_mega (or k_goldsum fallback) — no
  // global memset/atomic dispatch needed.
  if (threadIdx.x == 0) ws[OFF_GOLDP + blockIdx.x] = gacc;
}

// ---------------- fold16: 16-way semiring matrix fold (device fn) -----------
// tid in [0,256); threads >=144 inactive but participate in barriers.
__device__ __forceinline__ void fold16(
    float* __restrict__ ws, float* Ml, float* Vl, int tid, int s, int sem,
    int srcV, int srcF, int dstV, int dstVT, int dstF)
{
  int l = tid;
  bool act = (l < 144);
  int n = l / 12;
  int p = l - n * 12;
  int base = sem ? srcF : srcV;

  float V = (act && n == p) ? 0.f : -1.0e30f;
  float mreg = act ? ws[base + (s * 16) * 144 + l] : 0.f;

  for (int j = 0; j < 16; ++j) {
    if (act) { Ml[l] = mreg; Vl[l] = V; }
    __syncthreads();
    if (act) mreg = ws[base + (s * 16 + j + 1) * 144 + l];  // off-end: next region, safe
    if (act) {
      if (sem == 0) {
        float best = -3.0e38f;
        #pragma unroll
        for (int m = 0; m < R; ++m)
          best = fmaxf(best, Ml[n * 12 + m] + Vl[m * 12 + p]);
        V = best;
      } else {
        float cand[R]; float mx = -3.0e38f;
        #pragma unroll
        for (int m = 0; m < R; ++m) {
          cand[m] = Ml[n * 12 + m] + Vl[m * 12 + p];
          mx = fmaxf(mx, cand[m]);
        }
        float sum = 0.f;
        #pragma unroll
        for (int m = 0; m < R; ++m) sum += __expf(cand[m] - mx);
        V = mx + __logf(sum);
      }
    }
    __syncthreads();
  }
  if (act) {
    if (sem == 0) {
      ws[dstV  + s * 144 + n * 12 + p] = V;
      ws[dstVT + s * 144 + p * 12 + n] = V;
    } else {
      ws[dstF + s * 144 + n * 12 + p] = V;
    }
  }
}

// ---------------- K_mega: cooperative fusion of pass1..decode ---------------
// grid 256 x 256. Phase plan (grid.sync between each):
//   P0 pass1 (256 blk x 4 waves = 1024 virtual 64-thr units, exact old grid)
//   P1 fold1 (256 tasks, 1/block)     P2 fold2 (blk 0..15) + gold (blk 16)
//   P3 mid (blk 0)                    P4 expandA (blk 0..3)
//   P5 expandB (blk 0..63)            P6 decode (8 chunks/block)
__global__ __launch_bounds__(256) void k_mega(
    const float* __restrict__ trans, float* __restrict__ ws,
    float* __restrict__ out)
{
  cg::grid_group grid = cg::this_grid();
  const int tid = threadIdx.x;
  const int bid = blockIdx.x;

  __shared__ float Ml[144];
  __shared__ float Vl[144];
  __shared__ float Vmid[3][16];
  __shared__ float VexA[4][16];
  __shared__ float VexB[4][16];
  __shared__ float Vdec[8][16];
  __shared__ unsigned char bpd[8][SCH][16];
  __shared__ float gsh[256];

  // ================= P0: chunk transfer matrices (old k_pass1) =============
  {
    int gw   = bid * 4 + (tid >> 6);   // virtual 64-thr block id, [0,1024)
    int lane = tid & 63;
    int role = gw >> 9;
    int q = lane >> 4;
    int p = lane & 15;
    int c = (gw & 511) * 4 + q;
    int t0 = (c == 0) ? 1 : c * SCH;
    int t1 = c * SCH + SCH;
    bool act = (p < R);

    float Treg[R][R];

    if (role == 0) {
      #pragma unroll
      for (int n = 0; n < R; ++n)
        #pragma unroll
        for (int m = 0; m < R; ++m)
          Treg[n][m] = __expf(trans[n * NTAGS + m]);

      float E[R];
      #pragma unroll
      for (int m = 0; m < R; ++m) E[m] = (m == p) ? 1.f : 0.f;
      int kacc = 0;
      float sfeat = 0.f;

      float ef[R];
      load12(ws + OFF_EXPF + t0 * 12, ef);
      float fm = ws[OFF_FMAX + t0];

      for (int t = t0; t < t1; ++t) {
        float efn[R];
        load12(ws + OFF_EXPF + (t + 1) * 12, efn);   // off-end lands in FMAX: safe
        float fmn = ws[OFF_FMAX + t + 1];            // off-end lands in PF: safe
        sfeat += fm;
        float NE[R];
        #pragma unroll
        for (int n = 0; n < R; ++n) {
          float s = Treg[n][0] * E[0];
          #pragma unroll
          for (int m = 1; m < R; ++m) s = fmaf(Treg[n][m], E[m], s);
          NE[n] = s * ef[n];
        }
        #pragma unroll
        for (int n = 0; n < R; ++n) E[n] = NE[n];
        if ((t & 7) == 7) {
          float mx = E[0];
          #pragma unroll
          for (int n = 1; n < R; ++n) mx = fmaxf(mx, E[n]);
          if (mx > 0.f) {
            int k = ((__float_as_int(mx) >> 23) & 0xFF) - 127;
            float sc = __int_as_float((127 - k) << 23);
            #pragma unroll
            for (int n = 0; n < R; ++n) E[n] *= sc;
            kacc += k;
          }
        }
        #pragma unroll
        for (int n = 0; n < R; ++n) ef[n] = efn[n];
        fm = fmn;
      }
      if (act) {
        float base = (float)kacc * 0.6931471805599453f + sfeat;
        #pragma unroll
        for (int n = 0; n < R; ++n) {
          float v = (E[n] > 0.f) ? (__logf(E[n]) + base) : -1.0e30f;
          ws[OFF_PF + c * 144 + n * 12 + p] = v;
        }
      }
    } else {
      #pragma unroll
      for (int n = 0; n < R; ++n)
        #pragma unroll
        for (int m = 0; m < R; ++m)
          Treg[n][m] = trans[n * NTAGS + m];

      float V[R];
      #pragma unroll
      for (int m = 0; m < R; ++m) V[m] = (m == p) ? 0.f : -1.0e30f;

      float fr[R];
      load12(ws + OFF_FEATS + t0 * 12, fr);

      for (int t = t0; t < t1; ++t) {
        float frn[R];
        load12(ws + OFF_FEATS + (t + 1) * 12, frn);  // off-end lands in EXPF: safe
        float NV[R];
        #pragma unroll
        for (int n = 0; n < R; ++n) {
          float b = Treg[n][0] + V[0];
          #pragma unroll
          for (int m = 1; m < R; ++m) b = fmaxf(b, Treg[n][m] + V[m]);
          NV[n] = b + fr[n];
        }
        #pragma unroll
        for (int n = 0; n < R; ++n) { V[n] = NV[n]; fr[n] = frn[n]; }
      }
      if (act) {
        #pragma unroll
        for (int n = 0; n < R; ++n) {
          ws[OFF_PV  + c * 144 + n * 12 + p] = V[n];
          ws[OFF_PVC + c * 144 + p * 12 + n] = V[n];
        }
      }
    }
  }
  grid.sync();

  // ================= P1: fold1 — chunks -> supers ===========================
  fold16(ws, Ml, Vl, tid, bid >> 1, bid & 1,
         OFF_PV, OFF_PF, OFF_SMV, OFF_SMVT, OFF_SMF);
  grid.sync();

  // ================= P2: fold2 — supers -> hypers; gold reduce ==============
  if (bid < 16) {
    fold16(ws, Ml, Vl, tid, bid >> 1, bid & 1,
           OFF_SMV, OFF_SMF, OFF_HMV, OFF_HMVT, OFF_HMF);
  } else if (bid == 16) {
    float s = 0.f;
    for (int i = tid; i < CCH; i += 256) s += ws[OFF_GOLDP + i];
    gsh[tid] = s;
    __syncthreads();
    for (int off = 128; off > 0; off >>= 1) {
      if (tid < off) gsh[tid] += gsh[tid + off];
      __syncthreads();
    }
    if (tid == 0) ws[OFF_GOLD] = gsh[0];
  }
  grid.sync();

  // ================= P3: mid — sequential hyper-level scans (block 0) =======
  if (bid == 0) {
    int wid  = tid >> 6;
    int lane = tid & 63;
    int n = lane;
    bool act = (n < R);

    if (wid == 0) {
      // Viterbi forward -> HBV + path_score
      float x = -3.0e38f;
      if (act) {
        x = trans[n * NTAGS + T_START] + ws[OFF_FEATS + n];
        ws[OFF_HBV + n] = x;
        Vmid[0][n] = x;
      }
      float row[R], rown[R];
      if (act) load12(ws + OFF_HMV + n * 12, row);
      for (int h = 0; h < NHYP; ++h) {
        if (act) load12(ws + OFF_HMV + (h + 1) * 144 + n * 12, rown); // h=7: HMVT, unused
        float v[R];
        lds12(Vmid[0], v);
        if (act) {
          float nx = row[0] + v[0];
          #pragma unroll
          for (int m = 1; m < R; ++m) nx = fmaxf(nx, row[m] + v[m]);
          if (h < NHYP - 1) ws[OFF_HBV + (h + 1) * 12 + n] = nx;
          Vmid[0][n] = nx;
          #pragma unroll
          for (int m = 0; m < R; ++m) row[m] = rown[m];
        }
      }
      if (lane == 0) {
        float v[R];
        lds12(Vmid[0], v);
        float ps = -3.0e38f;
        #pragma unroll
        for (int m = 0; m < R; ++m) ps = fmaxf(ps, v[m] + trans[T_STOP * NTAGS + m]);
        out[1] = ps;
      }
    } else if (wid == 1) {
      // Viterbi suffix -> HSFX
      float x = -3.0e38f;
      if (act) {
        x = trans[T_STOP * NTAGS + n];
        ws[OFF_HSFX + (NHYP - 1) * 12 + n] = x;
        Vmid[1][n] = x;
      }
      float row[R], rown[R];
      if (act) load12(ws + OFF_HMVT + (NHYP - 1) * 144 + n * 12, row);
      for (int h = NHYP - 1; h >= 1; --h) {
        if (act) load12(ws + OFF_HMVT + (h - 1) * 144 + n * 12, rown);
        float v[R];
        lds12(Vmid[1], v);
        if (act) {
          float nx = row[0] + v[0];
          #pragma unroll
          for (int m = 1; m < R; ++m) nx = fmaxf(nx, row[m] + v[m]);
          ws[OFF_HSFX + (h - 1) * 12 + n] = nx;
          Vmid[1][n] = nx;
          #pragma unroll
          for (int m = 0; m < R; ++m) row[m] = rown[m];
        }
      }
    } else if (wid == 2) {
      // LSE forward -> nll
      float x = -3.0e38f;
      if (act) {
        x = trans[n * NTAGS + T_START] + ws[OFF_FEATS + n];
        Vmid[2][n] = x;
      }
      float row[R], rown[R];
      if (act) load12(ws + OFF_HMF + n * 12, row);
      for (int h = 0; h < NHYP; ++h) {
        if (act) load12(ws + OFF_HMF + (h + 1) * 144 + n * 12, rown); // h=7: SBV, unused
        float v[R];
        lds12(Vmid[2], v);
        if (act) {
          float tv[R]; float mx = -3.0e38f;
          #pragma unroll
          for (int m = 0; m < R; ++m) { tv[m] = row[m] + v[m]; mx = fmaxf(mx, tv[m]); }
          float sum = 0.f;
          #pragma unroll
          for (int m = 0; m < R; ++m) sum += __expf(tv[m] - mx);
          Vmid[2][n] = mx + __logf(sum);
          #pragma unroll
          for (int m = 0; m < R; ++m) row[m] = rown[m];
        }
      }
      if (lane == 0) {
        float v[R];
        lds12(Vmid[2], v);
        float mx = -3.0e38f;
        #pragma unroll
        for (int m = 0; m < R; ++m) mx = fmaxf(mx, v[m] + trans[T_STOP * NTAGS + m]);
        float sum = 0.f;
        #pragma unroll
        for (int m = 0; m < R; ++m) sum += __expf(v[m] + trans[T_STOP * NTAGS + m] - mx);
        out[0] = (mx + __logf(sum)) - ws[OFF_GOLD];
      }
    }
  }
  grid.sync();

  // ================= P4: expandA — hyper vectors -> super vectors ===========
  if (bid < 4 && tid < 64) {
    int q = tid >> 4;
    int g = tid & 15;
    int task = bid * 4 + q;
    int h = task >> 1;
    int dir = task & 1;
    bool act = (g < R);

    if (dir == 0) {
      float x = -3.0e38f;
      if (act) {
        x = ws[OFF_HBV + h * 12 + g];
        ws[OFF_SBV + (h * 16) * 12 + g] = x;
        VexA[q][g] = x;
      }
      float row[R], rown[R];
      if (act) load12(ws + OFF_SMV + (h * 16) * 144 + g * 12, row);
      for (int j = 0; j < 15; ++j) {
        int s = h * 16 + j;
        if (act) load12(ws + OFF_SMV + (s + 1) * 144 + g * 12, rown);
        float v[R];
        lds12(VexA[q], v);
        if (act) {
          float nx = row[0] + v[0];
          #pragma unroll
          for (int m = 1; m < R; ++m) nx = fmaxf(nx, row[m] + v[m]);
          ws[OFF_SBV + (s + 1) * 12 + g] = nx;
          VexA[q][g] = nx;
          #pragma unroll
          for (int m = 0; m < R; ++m) row[m] = rown[m];
        }
      }
    } else {
      float x = -3.0e38f;
      if (act) {
        x = ws[OFF_HSFX + h * 12 + g];
        ws[OFF_SSFX + (h * 16 + 15) * 12 + g] = x;
        VexA[q][g] = x;
      }
      float row[R], rown[R];
      if (act) load12(ws + OFF_SMVT + (h * 16 + 15) * 144 + g * 12, row);
      for (int j = 15; j >= 1; --j) {
        int s = h * 16 + j;
        if (act) load12(ws + OFF_SMVT + (s - 1) * 144 + g * 12, rown);
        float v[R];
        lds12(VexA[q], v);
        if (act) {
          float nx = row[0] + v[0];
          #pragma unroll
          for (int m = 1; m < R; ++m) nx = fmaxf(nx, row[m] + v[m]);
          ws[OFF_SSFX + (s - 1) * 12 + g] = nx;
          VexA[q][g] = nx;
          #pragma unroll
          for (int m = 0; m < R; ++m) row[m] = rown[m];
        }
      }
    }
  }
  grid.sync();

  // ================= P5: expandB — super vectors -> chunk vectors ===========
  if (bid < 64 && tid < 64) {
    int q = tid >> 4;
    int g = tid & 15;
    int task = bid * 4 + q;
    int s = task >> 1;
    int dir = task & 1;
    bool act = (g < R);

    if (dir == 0) {
      float x = -3.0e38f;
      if (act) {
        x = ws[OFF_SBV + s * 12 + g];
        ws[OFF_BV + (s * 16) * 12 + g] = x;
        VexB[q][g] = x;
      }
      float row[R], rown[R];
      if (act) load12(ws + OFF_PV + (s * 16) * 144 + g * 12, row);
      for (int j = 0; j < 15; ++j) {
        int c = s * 16 + j;
        if (act) load12(ws + OFF_PV + (c + 1) * 144 + g * 12, rown);
        float v[R];
        lds12(VexB[q], v);
        if (act) {
          float nx = row[0] + v[0];
          #pragma unroll
          for (int m = 1; m < R; ++m) nx = fmaxf(nx, row[m] + v[m]);
          ws[OFF_BV + (c + 1) * 12 + g] = nx;
          VexB[q][g] = nx;
          #pragma unroll
          for (int m = 0; m < R; ++m) row[m] = rown[m];
        }
      }
    } else {
      float x = -3.0e38f;
      if (act) {
        x = ws[OFF_SSFX + s * 12 + g];
        ws[OFF_SFX + (s * 16 + 15) * 12 + g] = x;
        VexB[q][g] = x;
      }
      float row[R], rown[R];
      if (act) load12(ws + OFF_PVC + (s * 16 + 15) * 144 + g * 12, row);
      for (int j = 15; j >= 1; --j) {
        int c = s * 16 + j;
        if (act) load12(ws + OFF_PVC + (c - 1) * 144 + g * 12, rown);
        float v[R];
        lds12(VexB[q], v);
        if (act) {
          float nx = row[0] + v[0];
          #pragma unroll
          for (int m = 1; m < R; ++m) nx = fmaxf(nx, row[m] + v[m]);
          ws[OFF_SFX + (c - 1) * 12 + g] = nx;
          VexB[q][g] = nx;
          #pragma unroll
          for (int m = 0; m < R; ++m) row[m] = rown[m];
        }
      }
    }
  }
  grid.sync();

  // ================= P6: decode — per-chunk re-scan + local backtrace =======
  {
    int q = tid >> 4;
    int g = tid & 15;
    if (q < 8) {
      int c = bid * 8 + q;
      int t0 = (c == 0) ? 1 : c * SCH;
      int t1 = c * SCH + SCH;
      bool act = (g < R);

      float treg[R];
      #pragma unroll
      for (int m = 0; m < R; ++m) treg[m] = act ? trans[g * NTAGS + m] : 0.f;

      float fv = act ? ws[OFF_BV + c * 12 + g] : -3.0e38f;
      Vdec[q][g] = fv;
      float fc = ws[OFF_FEATS + t0 * 12 + g];

      for (int t = t0; t < t1; ++t) {
        float fn = ws[OFF_FEATS + (t + 1) * 12 + g];   // off-end: EXPF, unused
        float v[R];
        lds12(Vdec[q], v);
        float best = -3.0e38f; int bi = 0;
        #pragma unroll
        for (int m = 0; m < R; ++m) {
          float cand = treg[m] + v[m];
          if (cand > best) { best = cand; bi = m; }
        }
        float nfv = best + fc;
        if (act) {
          bpd[q][t - t0][g] = (unsigned char)bi;
          Vdec[q][g] = nfv;
        }
        fc = fn;
      }

      Vdec[q][g] = act ? (Vdec[q][g] + ws[OFF_SFX + c * 12 + g]) : -3.0e38f;

      if (g == 0) {
        float best = Vdec[q][0]; int idx = 0;
        #pragma unroll
        for (int m = 1; m < R; ++m) {
          float v = Vdec[q][m];
          if (v > best) { best = v; idx = m; }
        }
        int cur = idx;
        int len = t1 - t0;
        out[2 + t0 + len - 1] = (float)cur;
        for (int tt = len - 1; tt >= 1; --tt) {
          cur = bpd[q][tt][cur];
          out[2 + t0 + tt - 1] = (float)cur;
        }
        if (c == 0) {
          cur = bpd[q][0][cur];
          out[2 + 0] = (float)cur;
        }
      }
    }
  }
}

// ======================= fallback path (original chain) =====================

__global__ __launch_bounds__(256) void k_goldsum(float* __restrict__ ws)
{
  __shared__ float gsh[256];
  float s = 0.f;
  for (int i = threadIdx.x; i < CCH; i += 256) s += ws[OFF_GOLDP + i];
  gsh[threadIdx.x] = s;
  __syncthreads();
  for (int off = 128; off > 0; off >>= 1) {
    if (threadIdx.x < off) gsh[threadIdx.x] += gsh[threadIdx.x + off];
    __syncthreads();
  }
  if (threadIdx.x == 0) ws[OFF_GOLD] = gsh[0];
}

__global__ __launch_bounds__(64) void k_pass1(
    const float* __restrict__ trans, float* __restrict__ ws)
{
  int role = blockIdx.x >> 9;
  int q = threadIdx.x >> 4;
  int p = threadIdx.x & 15;
  int c = (blockIdx.x & 511) * 4 + q;
  int t0 = (c == 0) ? 1 : c * SCH;
  int t1 = c * SCH + SCH;
  bool act = (p < R);

  float Treg[R][R];

  if (role == 0) {
    #pragma unroll
    for (int n = 0; n < R; ++n)
      #pragma unroll
      for (int m = 0; m < R; ++m)
        Treg[n][m] = __expf(trans[n * NTAGS + m]);

    float E[R];
    #pragma unroll
    for (int m = 0; m < R; ++m) E[m] = (m == p) ? 1.f : 0.f;
    int kacc = 0;
    float sfeat = 0.f;

    float ef[R];
    load12(ws + OFF_EXPF + t0 * 12, ef);
    float fm = ws[OFF_FMAX + t0];

    for (int t = t0; t < t1; ++t) {
      float efn[R];
      load12(ws + OFF_EXPF + (t + 1) * 12, efn);
      float fmn = ws[OFF_FMAX + t + 1];
      sfeat += fm;
      float NE[R];
      #pragma unroll
      for (int n = 0; n < R; ++n) {
        float s = Treg[n][0] * E[0];
        #pragma unroll
        for (int m = 1; m < R; ++m) s = fmaf(Treg[n][m], E[m], s);
        NE[n] = s * ef[n];
      }
      #pragma unroll
      for (int n = 0; n < R; ++n) E[n] = NE[n];
      if ((t & 7) == 7) {
        float mx = E[0];
        #pragma unroll
        for (int n = 1; n < R; ++n) mx = fmaxf(mx, E[n]);
        if (mx > 0.f) {
          int k = ((__float_as_int(mx) >> 23) & 0xFF) - 127;
          float sc = __int_as_float((127 - k) << 23);
          #pragma unroll
          for (int n = 0; n < R; ++n) E[n] *= sc;
          kacc += k;
        }
      }
      #pragma unroll
      for (int n = 0; n < R; ++n) ef[n] = efn[n];
      fm = fmn;
    }
    if (act) {
      float base = (float)kacc * 0.6931471805599453f + sfeat;
      #pragma unroll
      for (int n = 0; n < R; ++n) {
        float v = (E[n] > 0.f) ? (__logf(E[n]) + base) : -1.0e30f;
        ws[OFF_PF + c * 144 + n * 12 + p] = v;
      }
    }
  } else {
    #pragma unroll
    for (int n = 0; n < R; ++n)
      #pragma unroll
      for (int m = 0; m < R; ++m)
        Treg[n][m] = trans[n * NTAGS + m];

    float V[R];
    #pragma unroll
    for (int m = 0; m < R; ++m) V[m] = (m == p) ? 0.f : -1.0e30f;

    float fr[R];
    load12(ws + OFF_FEATS + t0 * 12, fr);

    for (int t = t0; t < t1; ++t) {
      float frn[R];
      load12(ws + OFF_FEATS + (t + 1) * 12, frn);
      float NV[R];
      #pragma unroll
      for (int n = 0; n < R; ++n) {
        float b = Treg[n][0] + V[0];
        #pragma unroll
        for (int m = 1; m < R; ++m) b = fmaxf(b, Treg[n][m] + V[m]);
        NV[n] = b + fr[n];
      }
      #pragma unroll
      for (int n = 0; n < R; ++n) { V[n] = NV[n]; fr[n] = frn[n]; }
    }
    if (act) {
      #pragma unroll
      for (int n = 0; n < R; ++n) {
        ws[OFF_PV  + c * 144 + n * 12 + p] = V[n];
        ws[OFF_PVC + c * 144 + p * 12 + n] = V[n];
      }
    }
  }
}

__global__ __launch_bounds__(192) void k_fold(
    float* __restrict__ ws, int srcV, int srcF, int dstV, int dstVT, int dstF)
{
  __shared__ float Ml[144];
  __shared__ float Vl[144];
  int s   = blockIdx.x >> 1;
  int sem = blockIdx.x & 1;
  int l = threadIdx.x;
  bool act = (l < 144);
  int n = l / 12;
  int p = l - n * 12;
  int base = sem ? srcF : srcV;

  float V = (act && n == p) ? 0.f : -1.0e30f;
  float mreg = act ? ws[base + (s * 16) * 144 + l] : 0.f;

  for (int j = 0; j < 16; ++j) {
    if (act) { Ml[l] = mreg; Vl[l] = V; }
    __syncthreads();
    if (act) mreg = ws[base + (s * 16 + j + 1) * 144 + l];
    if (act) {
      if (sem == 0) {
        float best = -3.0e38f;
        #pragma unroll
        for (int m = 0; m < R; ++m)
          best = fmaxf(best, Ml[n * 12 + m] + Vl[m * 12 + p]);
        V = best;
      } else {
        float cand[R]; float mx = -3.0e38f;
        #pragma unroll
        for (int m = 0; m < R; ++m) {
          cand[m] = Ml[n * 12 + m] + Vl[m * 12 + p];
          mx = fmaxf(mx, cand[m]);
        }
        float sum = 0.f;
        #pragma unroll
        for (int m = 0; m < R; ++m) sum += __expf(cand[m] - mx);
        V = mx + __logf(sum);
      }
    }
    __syncthreads();
  }
  if (act) {
    if (sem == 0) {
      ws[dstV  + s * 144 + n * 12 + p] = V;
      ws[dstVT + s * 144 + p * 12 + n] = V;
    } else {
      ws[dstF + s * 144 + n * 12 + p] = V;
    }
  }
}

__global__ __launch_bounds__(192) void k_mid(
    const float* __restrict__ trans, float* __restrict__ ws,
    float* __restrict__ out)
{
  __shared__ float Vsh[3][16];
  int wid  = threadIdx.x >> 6;
  int lane = threadIdx.x & 63;
  int n = lane;
  bool act = (n < R);

  if (wid == 0) {
    float x = -3.0e38f;
    if (act) {
      x = trans[n * NTAGS + T_START] + ws[OFF_FEATS + n];
      ws[OFF_HBV + n] = x;
      Vsh[0][n] = x;
    }
    float row[R], rown[R];
    if (act) load12(ws + OFF_HMV + n * 12, row);
    for (int h = 0; h < NHYP; ++h) {
      if (act) load12(ws + OFF_HMV + (h + 1) * 144 + n * 12, rown);
      float v[R];
      lds12(Vsh[0], v);
      if (act) {
        float nx = row[0] + v[0];
        #pragma unroll
        for (int m = 1; m < R; ++m) nx = fmaxf(nx, row[m] + v[m]);
        if (h < NHYP - 1) ws[OFF_HBV + (h + 1) * 12 + n] = nx;
        Vsh[0][n] = nx;
        #pragma unroll
        for (int m = 0; m < R; ++m) row[m] = rown[m];
      }
    }
    if (lane == 0) {
      float v[R];
      lds12(Vsh[0], v);
      float ps = -3.0e38f;
      #pragma unroll
      for (int m = 0; m < R; ++m) ps = fmaxf(ps, v[m] + trans[T_STOP * NTAGS + m]);
      out[1] = ps;
    }
  } else if (wid == 1) {
    float x = -3.0e38f;
    if (act) {
      x = trans[T_STOP * NTAGS + n];
      ws[OFF_HSFX + (NHYP - 1) * 12 + n] = x;
      Vsh[1][n] = x;
    }
    float row[R], rown[R];
    if (act) load12(ws + OFF_HMVT + (NHYP - 1) * 144 + n * 12, row);
    for (int h = NHYP - 1; h >= 1; --h) {
      if (act) load12(ws + OFF_HMVT + (h - 1) * 144 + n * 12, rown);
      float v[R];
      lds12(Vsh[1], v);
      if (act) {
        float nx = row[0] + v[0];
        #pragma unroll
        for (int m = 1; m < R; ++m) nx = fmaxf(nx, row[m] + v[m]);
        ws[OFF_HSFX + (h - 1) * 12 + n] = nx;
        Vsh[1][n] = nx;
        #pragma unroll
        for (int m = 0; m < R; ++m) row[m] = rown[m];
      }
    }
  } else if (wid == 2) {
    float x = -3.0e38f;
    if (act) {
      x = trans[n * NTAGS + T_START] + ws[OFF_FEATS + n];
      Vsh[2][n] = x;
    }
    float row[R], rown[R];
    if (act) load12(ws + OFF_HMF + n * 12, row);
    for (int h = 0; h < NHYP; ++h) {
      if (act) load12(ws + OFF_HMF + (h + 1) * 144 + n * 12, rown);
      float v[R];
      lds12(Vsh[2], v);
      if (act) {
        float tv[R]; float mx = -3.0e38f;
        #pragma unroll
        for (int m = 0; m < R; ++m) { tv[m] = row[m] + v[m]; mx = fmaxf(mx, tv[m]); }
        float sum = 0.f;
        #pragma unroll
        for (int m = 0; m < R; ++m) sum += __expf(tv[m] - mx);
        Vsh[2][n] = mx + __logf(sum);
        #pragma unroll
        for (int m = 0; m < R; ++m) row[m] = rown[m];
      }
    }
    if (lane == 0) {
      float v[R];
      lds12(Vsh[2], v);
      float mx = -3.0e38f;
      #pragma unroll
      for (int m = 0; m < R; ++m) mx = fmaxf(mx, v[m] + trans[T_STOP * NTAGS + m]);
      float sum = 0.f;
      #pragma unroll
      for (int m = 0; m < R; ++m) sum += __expf(v[m] + trans[T_STOP * NTAGS + m] - mx);
      out[0] = (mx + __logf(sum)) - ws[OFF_GOLD];
    }
  }
}

__global__ __launch_bounds__(64) void k_expandA(
    float* __restrict__ ws)
{
  __shared__ float Vsh[4][16];
  int q = threadIdx.x >> 4;
  int g = threadIdx.x & 15;
  int task = blockIdx.x * 4 + q;
  int h = task >> 1;
  int dir = task & 1;
  bool act = (g < R);

  if (dir == 0) {
    float x = -3.0e38f;
    if (act) {
      x = ws[OFF_HBV + h * 12 + g];
      ws[OFF_SBV + (h * 16) * 12 + g] = x;
      Vsh[q][g] = x;
    }
    float row[R], rown[R];
    if (act) load12(ws + OFF_SMV + (h * 16) * 144 + g * 12, row);
    for (int j = 0; j < 15; ++j) {
      int s = h * 16 + j;
      if (act) load12(ws + OFF_SMV + (s + 1) * 144 + g * 12, rown);
      float v[R];
      lds12(Vsh[q], v);
      if (act) {
        float nx = row[0] + v[0];
        #pragma unroll
        for (int m = 1; m < R; ++m) nx = fmaxf(nx, row[m] + v[m]);
        ws[OFF_SBV + (s + 1) * 12 + g] = nx;
        Vsh[q][g] = nx;
        #pragma unroll
        for (int m = 0; m < R; ++m) row[m] = rown[m];
      }
    }
  } else {
    float x = -3.0e38f;
    if (act) {
      x = ws[OFF_HSFX + h * 12 + g];
      ws[OFF_SSFX + (h * 16 + 15) * 12 + g] = x;
      Vsh[q][g] = x;
    }
    float row[R], rown[R];
    if (act) load12(ws + OFF_SMVT + (h * 16 + 15) * 144 + g * 12, row);
    for (int j = 15; j >= 1; --j) {
      int s = h * 16 + j;
      if (act) load12(ws + OFF_SMVT + (s - 1) * 144 + g * 12, rown);
      float v[R];
      lds12(Vsh[q], v);
      if (act) {
        float nx = row[0] + v[0];
        #pragma unroll
        for (int m = 1; m < R; ++m) nx = fmaxf(nx, row[m] + v[m]);
        ws[OFF_SSFX + (s - 1) * 12 + g] = nx;
        Vsh[q][g] = nx;
        #pragma unroll
        for (int m = 0; m < R; ++m) row[m] = rown[m];
      }
    }
  }
}

__global__ __launch_bounds__(64) void k_expandB(
    float* __restrict__ ws)
{
  __shared__ float Vsh[4][16];
  int q = threadIdx.x >> 4;
  int g = threadIdx.x & 15;
  int task = blockIdx.x * 4 + q;
  int s = task >> 1;
  int dir = task & 1;
  bool act = (g < R);

  if (dir == 0) {
    float x = -3.0e38f;
    if (act) {
      x = ws[OFF_SBV + s * 12 + g];
      ws[OFF_BV + (s * 16) * 12 + g] = x;
      Vsh[q][g] = x;
    }
    float row[R], rown[R];
    if (act) load12(ws + OFF_PV + (s * 16) * 144 + g * 12, row);
    for (int j = 0; j < 15; ++j) {
      int c = s * 16 + j;
      if (act) load12(ws + OFF_PV + (c + 1) * 144 + g * 12, rown);
      float v[R];
      lds12(Vsh[q], v);
      if (act) {
        float nx = row[0] + v[0];
        #pragma unroll
        for (int m = 1; m < R; ++m) nx = fmaxf(nx, row[m] + v[m]);
        ws[OFF_BV + (c + 1) * 12 + g] = nx;
        Vsh[q][g] = nx;
        #pragma unroll
        for (int m = 0; m < R; ++m) row[m] = rown[m];
      }
    }
  } else {
    float x = -3.0e38f;
    if (act) {
      x = ws[OFF_SSFX + s * 12 + g];
      ws[OFF_SFX + (s * 16 + 15) * 12 + g] = x;
      Vsh[q][g] = x;
    }
    float row[R], rown[R];
    if (act) load12(ws + OFF_PVC + (s * 16 + 15) * 144 + g * 12, row);
    for (int j = 15; j >= 1; --j) {
      int c = s * 16 + j;
      if (act) load12(ws + OFF_PVC + (c - 1) * 144 + g * 12, rown);
      float v[R];
      lds12(Vsh[q], v);
      if (act) {
        float nx = row[0] + v[0];
        #pragma unroll
        for (int m = 1; m < R; ++m) nx = fmaxf(nx, row[m] + v[m]);
        ws[OFF_SFX + (c - 1) * 12 + g] = nx;
        Vsh[q][g] = nx;
        #pragma unroll
        for (int m = 0; m < R; ++m) row[m] = rown[m];
      }
    }
  }
}

__global__ __launch_bounds__(64) void k_decode(
    const float* __restrict__ trans, const float* __restrict__ ws,
    float* __restrict__ out)
{
  __shared__ unsigned char bp[4][SCH][16];
  __shared__ float Vsh[4][16];
  int q = threadIdx.x >> 4;
  int g = threadIdx.x & 15;
  int c = blockIdx.x * 4 + q;
  int t0 = (c == 0) ? 1 : c * SCH;
  int t1 = c * SCH + SCH;
  bool act = (g < R);

  float treg[R];
  #pragma unroll
  for (int m = 0; m < R; ++m) treg[m] = act ? trans[g * NTAGS + m] : 0.f;

  float fv = act ? ws[OFF_BV + c * 12 + g] : -3.0e38f;
  Vsh[q][g] = fv;
  float fc = ws[OFF_FEATS + t0 * 12 + g];

  for (int t = t0; t < t1; ++t) {
    float fn = ws[OFF_FEATS + (t + 1) * 12 + g];
    float v[R];
    lds12(Vsh[q], v);
    float best = -3.0e38f; int bi = 0;
    #pragma unroll
    for (int m = 0; m < R; ++m) {
      float cand = treg[m] + v[m];
      if (cand > best) { best = cand; bi = m; }
    }
    float nfv = best + fc;
    if (act) {
      bp[q][t - t0][g] = (unsigned char)bi;
      Vsh[q][g] = nfv;
    }
    fc = fn;
  }

  Vsh[q][g] = act ? (Vsh[q][g] + ws[OFF_SFX + c * 12 + g]) : -3.0e38f;

  if (g == 0) {
    float best = Vsh[q][0]; int idx = 0;
    #pragma unroll
    for (int m = 1; m < R; ++m) {
      float v = Vsh[q][m];
      if (v > best) { best = v; idx = m; }
    }
    int cur = idx;
    int len = t1 - t0;
    out[2 + t0 + len - 1] = (float)cur;
    for (int tt = len - 1; tt >= 1; --tt) {
      cur = bp[q][tt][cur];
      out[2 + t0 + tt - 1] = (float)cur;
    }
    if (c == 0) {
      cur = bp[q][0][cur];
      out[2 + 0] = (float)cur;
    }
  }
}

extern "C" void kernel_launch(void* const* d_in, const int* in_sizes, int n_in,
                              void* d_out, int out_size, void* d_ws, size_t ws_size,
                              hipStream_t stream) {
  (void)in_sizes; (void)n_in; (void)out_size; (void)ws_size;
  const int*   sentence = (const int*)d_in[0];
  const int*   tags     = (const int*)d_in[1];
  const float* emb      = (const float*)d_in[2];
  const float* W        = (const float*)d_in[3];
  const float* trans    = (const float*)d_in[4];
  float* ws  = (float*)d_ws;
  float* out = (float*)d_out;

  k_feats<<<LSEQ / 16, 256, 0, stream>>>(sentence, tags, emb, W, trans, ws);

  void* kargs[] = { (void*)&trans, (void*)&ws, (void*)&out };
  hipError_t ce = hipLaunchCooperativeKernel((const void*)k_mega, dim3(256),
                                             dim3(256), kargs, 0, stream);
  if (ce != hipSuccess) {
    // fallback: original 8-dispatch chain (k_goldsum replaces the memset)
    k_goldsum<<<1, 256, 0, stream>>>(ws);
    k_pass1<<<1024, 64, 0, stream>>>(trans, ws);
    k_fold<<<NSUP * 2, 192, 0, stream>>>(ws, OFF_PV, OFF_PF, OFF_SMV, OFF_SMVT, OFF_SMF);
    k_fold<<<NHYP * 2, 192, 0, stream>>>(ws, OFF_SMV, OFF_SMF, OFF_HMV, OFF_HMVT, OFF_HMF);
    k_mid<<<1, 192, 0, stream>>>(trans, ws, out);
    k_expandA<<<4, 64, 0, stream>>>(ws);
    k_expandB<<<64, 64, 0, stream>>>(ws);
    k_decode<<<CCH / 4, 64, 0, stream>>>(trans, ws, out);
  }
}

// Round 2
// 397.192 us; speedup vs baseline: 1.0829x; 1.0829x over previous
//
#include <hip/hip_runtime.h>
#include <hip/hip_cooperative_groups.h>

namespace cg = cooperative_groups;

// EmbeddingCRF: feats = emb[sentence] @ W^T; CRF forward (LSE), gold score,
// Viterbi decode. Parallel-in-time via 12x12 semiring transfer matrices.
// R4: 4-level scan tree — 2048 chunks(16) -> 128 supers -> 8 hypers -> seq 8.
// R6: R5's full fusion spilled: pass1 needs Treg[12][12]=144 VGPR/thread but
// the 256-thread coop kernel got only 108 VGPRs -> scratch spills -> 219us
// (4% VALUBusy). Fix: split on register pressure. k_feats and k_pass1 keep
// their own dispatches (own register budgets, proven allocations); only the
// register-light tail (fold1/fold2+gold/mid/expandA/expandB/decode, all
// <~60 VGPR) is fused into one cooperative kernel with 5 grid.sync()s.
// 10 dispatches (R4) -> 3.

#define LSEQ    32768
#define NTAGS   14
#define R       12
#define T_START 12
#define T_STOP  13
#define EMBD    300
#define CCH     2048  // chunks
#define SCH     16    // steps per chunk
#define NSUP    128   // supers (16 chunks each)
#define NHYP    8     // hypers (16 supers each)

// ws layout (float offsets)
#define OFF_FEATS 0         // [L][12]
#define OFF_EXPF  393216    // [L][12]
#define OFF_FMAX  786432    // [L]
#define OFF_PF    819200    // [2048][n][p] LSE chunk mats (log domain)
#define OFF_PV    1114112   // [2048][n][p] max-plus chunk mats
#define OFF_PVC   1409024   // [2048][p][n] transposed
#define OFF_BV    1703936   // [2048][12] viterbi entry vectors
#define OFF_SFX   1728512   // [2048][12] viterbi suffix vectors
#define OFF_GOLD  1753088   // [1]
#define OFF_SMV   1753104   // [128][n][p]
#define OFF_SMVT  1771536   // [128][p][n]
#define OFF_SMF   1789968   // [128][n][p]
#define OFF_HMV   1808400   // [8][n][p]
#define OFF_HMVT  1809552   // [8][p][n]
#define OFF_HMF   1810704   // [8][n][p]
#define OFF_SBV   1811856   // [128][12]
#define OFF_SSFX  1813392   // [128][12]
#define OFF_HBV   1814928   // [8][12]
#define OFF_HSFX  1815024   // [8][12]
#define OFF_GOLDP 1815120   // [2048] per-block gold partials

__device__ __forceinline__ void load12(const float* __restrict__ p, float* r) {
  const float4* p4 = (const float4*)p;
  float4 a = p4[0], b = p4[1], c = p4[2];
  r[0]=a.x; r[1]=a.y; r[2]=a.z; r[3]=a.w;
  r[4]=b.x; r[5]=b.y; r[6]=b.z; r[7]=b.w;
  r[8]=c.x; r[9]=c.y; r[10]=c.z; r[11]=c.w;
}

__device__ __forceinline__ void lds12(const float* p, float* r) {
  const float4* p4 = (const float4*)p;
  float4 a = p4[0], b = p4[1], c = p4[2];
  r[0]=a.x; r[1]=a.y; r[2]=a.z; r[3]=a.w;
  r[4]=b.x; r[5]=b.y; r[6]=b.z; r[7]=b.w;
  r[8]=c.x; r[9]=c.y; r[10]=c.z; r[11]=c.w;
}

// ---------------- K1: feats + expfeat + featmax + gold partials -------------
__global__ __launch_bounds__(256) void k_feats(
    const int* __restrict__ sentence, const int* __restrict__ tags,
    const float* __restrict__ emb, const float* __restrict__ W,
    const float* __restrict__ trans, float* __restrict__ ws)
{
  __shared__ float Wl[NTAGS * EMBD];
  __shared__ float gacc;
  for (int i = threadIdx.x; i < NTAGS * EMBD; i += 256) Wl[i] = W[i];
  if (threadIdx.x == 0) gacc = 0.f;
  __syncthreads();

  int grp = threadIdx.x >> 4;
  int g   = threadIdx.x & 15;
  int pos = blockIdx.x * 16 + grp;
  int row = sentence[pos];

  float acc = 0.f;
  if (g < R) {
    const float4* e4 = (const float4*)(emb + (size_t)row * EMBD);
    const float4* w4 = (const float4*)(Wl + g * EMBD);
    #pragma unroll 5
    for (int i = 0; i < EMBD / 4; ++i) {
      float4 a = e4[i]; float4 b = w4[i];
      acc += a.x*b.x + a.y*b.y + a.z*b.z + a.w*b.w;
    }
  }
  float feat = (g < R) ? acc : -3.0e38f;
  float mx = feat;
  #pragma unroll
  for (int off = 1; off < 16; off <<= 1)
    mx = fmaxf(mx, __shfl_xor(mx, off, 16));

  if (g < R) {
    ws[OFF_FEATS + pos * 12 + g] = feat;
    ws[OFF_EXPF  + pos * 12 + g] = __expf(feat - mx);
  }
  if (g == 0) ws[OFF_FMAX + pos] = mx;

  int tg = tags[pos];
  if (g == tg) {
    int prev = (pos == 0) ? T_START : tags[pos - 1];
    float gc = feat + trans[tg * NTAGS + prev];
    if (pos == LSEQ - 1) gc += trans[T_STOP * NTAGS + tg];
    atomicAdd(&gacc, gc);
  }
  __syncthreads();
  if (threadIdx.x == 0) ws[OFF_GOLDP + blockIdx.x] = gacc;
}

// ---------------- K2: chunk transfer matrices (standalone, own reg budget) --
// 1024 blocks x 64 thr: blocks 0..511 LSE, 512..1023 viterbi; 4 chunks/block.
__global__ __launch_bounds__(64) void k_pass1(
    const float* __restrict__ trans, float* __restrict__ ws)
{
  int role = blockIdx.x >> 9;
  int q = threadIdx.x >> 4;
  int p = threadIdx.x & 15;
  int c = (blockIdx.x & 511) * 4 + q;
  int t0 = (c == 0) ? 1 : c * SCH;
  int t1 = c * SCH + SCH;
  bool act = (p < R);

  float Treg[R][R];

  if (role == 0) {
    #pragma unroll
    for (int n = 0; n < R; ++n)
      #pragma unroll
      for (int m = 0; m < R; ++m)
        Treg[n][m] = __expf(trans[n * NTAGS + m]);

    float E[R];
    #pragma unroll
    for (int m = 0; m < R; ++m) E[m] = (m == p) ? 1.f : 0.f;
    int kacc = 0;
    float sfeat = 0.f;

    float ef[R];
    load12(ws + OFF_EXPF + t0 * 12, ef);
    float fm = ws[OFF_FMAX + t0];

    for (int t = t0; t < t1; ++t) {
      float efn[R];
      load12(ws + OFF_EXPF + (t + 1) * 12, efn);   // off-end lands in FMAX: safe
      float fmn = ws[OFF_FMAX + t + 1];            // off-end lands in PF: safe
      sfeat += fm;
      float NE[R];
      #pragma unroll
      for (int n = 0; n < R; ++n) {
        float s = Treg[n][0] * E[0];
        #pragma unroll
        for (int m = 1; m < R; ++m) s = fmaf(Treg[n][m], E[m], s);
        NE[n] = s * ef[n];
      }
      #pragma unroll
      for (int n = 0; n < R; ++n) E[n] = NE[n];
      if ((t & 7) == 7) {
        float mx = E[0];
        #pragma unroll
        for (int n = 1; n < R; ++n) mx = fmaxf(mx, E[n]);
        if (mx > 0.f) {
          int k = ((__float_as_int(mx) >> 23) & 0xFF) - 127;
          float sc = __int_as_float((127 - k) << 23);
          #pragma unroll
          for (int n = 0; n < R; ++n) E[n] *= sc;
          kacc += k;
        }
      }
      #pragma unroll
      for (int n = 0; n < R; ++n) ef[n] = efn[n];
      fm = fmn;
    }
    if (act) {
      float base = (float)kacc * 0.6931471805599453f + sfeat;
      #pragma unroll
      for (int n = 0; n < R; ++n) {
        float v = (E[n] > 0.f) ? (__logf(E[n]) + base) : -1.0e30f;
        ws[OFF_PF + c * 144 + n * 12 + p] = v;
      }
    }
  } else {
    #pragma unroll
    for (int n = 0; n < R; ++n)
      #pragma unroll
      for (int m = 0; m < R; ++m)
        Treg[n][m] = trans[n * NTAGS + m];

    float V[R];
    #pragma unroll
    for (int m = 0; m < R; ++m) V[m] = (m == p) ? 0.f : -1.0e30f;

    float fr[R];
    load12(ws + OFF_FEATS + t0 * 12, fr);

    for (int t = t0; t < t1; ++t) {
      float frn[R];
      load12(ws + OFF_FEATS + (t + 1) * 12, frn);  // off-end lands in EXPF: safe
      float NV[R];
      #pragma unroll
      for (int n = 0; n < R; ++n) {
        float b = Treg[n][0] + V[0];
        #pragma unroll
        for (int m = 1; m < R; ++m) b = fmaxf(b, Treg[n][m] + V[m]);
        NV[n] = b + fr[n];
      }
      #pragma unroll
      for (int n = 0; n < R; ++n) { V[n] = NV[n]; fr[n] = frn[n]; }
    }
    if (act) {
      #pragma unroll
      for (int n = 0; n < R; ++n) {
        ws[OFF_PV  + c * 144 + n * 12 + p] = V[n];
        ws[OFF_PVC + c * 144 + p * 12 + n] = V[n];
      }
    }
  }
}

// ---------------- fold16: 16-way semiring matrix fold (device fn) -----------
__device__ __forceinline__ void fold16(
    float* __restrict__ ws, float* Ml, float* Vl, int tid, int s, int sem,
    int srcV, int srcF, int dstV, int dstVT, int dstF)
{
  int l = tid;
  bool act = (l < 144);
  int n = l / 12;
  int p = l - n * 12;
  int base = sem ? srcF : srcV;

  float V = (act && n == p) ? 0.f : -1.0e30f;
  float mreg = act ? ws[base + (s * 16) * 144 + l] : 0.f;

  for (int j = 0; j < 16; ++j) {
    if (act) { Ml[l] = mreg; Vl[l] = V; }
    __syncthreads();
    if (act) mreg = ws[base + (s * 16 + j + 1) * 144 + l];  // off-end: next region, safe
    if (act) {
      if (sem == 0) {
        float best = -3.0e38f;
        #pragma unroll
        for (int m = 0; m < R; ++m)
          best = fmaxf(best, Ml[n * 12 + m] + Vl[m * 12 + p]);
        V = best;
      } else {
        float cand[R]; float mx = -3.0e38f;
        #pragma unroll
        for (int m = 0; m < R; ++m) {
          cand[m] = Ml[n * 12 + m] + Vl[m * 12 + p];
          mx = fmaxf(mx, cand[m]);
        }
        float sum = 0.f;
        #pragma unroll
        for (int m = 0; m < R; ++m) sum += __expf(cand[m] - mx);
        V = mx + __logf(sum);
      }
    }
    __syncthreads();
  }
  if (act) {
    if (sem == 0) {
      ws[dstV  + s * 144 + n * 12 + p] = V;
      ws[dstVT + s * 144 + p * 12 + n] = V;
    } else {
      ws[dstF + s * 144 + n * 12 + p] = V;
    }
  }
}

// ---------------- K_mega2: cooperative fusion of fold1..decode --------------
// grid 256 x 256 — all phases are register-light (<~60 VGPR). Phase plan:
//   P1 fold1 (256 tasks, 1/block)     P2 fold2 (blk 0..15) + gold (blk 16)
//   P3 mid (blk 0)                    P4 expandA (blk 0..3)
//   P5 expandB (blk 0..63)            P6 decode (8 chunks/block)
__global__ __launch_bounds__(256) void k_mega2(
    const float* __restrict__ trans, float* __restrict__ ws,
    float* __restrict__ out)
{
  cg::grid_group grid = cg::this_grid();
  const int tid = threadIdx.x;
  const int bid = blockIdx.x;

  __shared__ float Ml[144];
  __shared__ float Vl[144];
  __shared__ float Vmid[3][16];
  __shared__ float VexA[4][16];
  __shared__ float VexB[4][16];
  __shared__ float Vdec[8][16];
  __shared__ unsigned char bpd[8][SCH][16];
  __shared__ float gsh[256];

  // ================= P1: fold1 — chunks -> supers ===========================
  fold16(ws, Ml, Vl, tid, bid >> 1, bid & 1,
         OFF_PV, OFF_PF, OFF_SMV, OFF_SMVT, OFF_SMF);
  grid.sync();

  // ================= P2: fold2 — supers -> hypers; gold reduce ==============
  if (bid < 16) {
    fold16(ws, Ml, Vl, tid, bid >> 1, bid & 1,
           OFF_SMV, OFF_SMF, OFF_HMV, OFF_HMVT, OFF_HMF);
  } else if (bid == 16) {
    float s = 0.f;
    for (int i = tid; i < CCH; i += 256) s += ws[OFF_GOLDP + i];
    gsh[tid] = s;
    __syncthreads();
    for (int off = 128; off > 0; off >>= 1) {
      if (tid < off) gsh[tid] += gsh[tid + off];
      __syncthreads();
    }
    if (tid == 0) ws[OFF_GOLD] = gsh[0];
  }
  grid.sync();

  // ================= P3: mid — sequential hyper-level scans (block 0) =======
  if (bid == 0) {
    int wid  = tid >> 6;
    int lane = tid & 63;
    int n = lane;
    bool act = (n < R);

    if (wid == 0) {
      // Viterbi forward -> HBV + path_score
      float x = -3.0e38f;
      if (act) {
        x = trans[n * NTAGS + T_START] + ws[OFF_FEATS + n];
        ws[OFF_HBV + n] = x;
        Vmid[0][n] = x;
      }
      float row[R], rown[R];
      if (act) load12(ws + OFF_HMV + n * 12, row);
      for (int h = 0; h < NHYP; ++h) {
        if (act) load12(ws + OFF_HMV + (h + 1) * 144 + n * 12, rown); // h=7: HMVT, unused
        float v[R];
        lds12(Vmid[0], v);
        if (act) {
          float nx = row[0] + v[0];
          #pragma unroll
          for (int m = 1; m < R; ++m) nx = fmaxf(nx, row[m] + v[m]);
          if (h < NHYP - 1) ws[OFF_HBV + (h + 1) * 12 + n] = nx;
          Vmid[0][n] = nx;
          #pragma unroll
          for (int m = 0; m < R; ++m) row[m] = rown[m];
        }
      }
      if (lane == 0) {
        float v[R];
        lds12(Vmid[0], v);
        float ps = -3.0e38f;
        #pragma unroll
        for (int m = 0; m < R; ++m) ps = fmaxf(ps, v[m] + trans[T_STOP * NTAGS + m]);
        out[1] = ps;
      }
    } else if (wid == 1) {
      // Viterbi suffix -> HSFX
      float x = -3.0e38f;
      if (act) {
        x = trans[T_STOP * NTAGS + n];
        ws[OFF_HSFX + (NHYP - 1) * 12 + n] = x;
        Vmid[1][n] = x;
      }
      float row[R], rown[R];
      if (act) load12(ws + OFF_HMVT + (NHYP - 1) * 144 + n * 12, row);
      for (int h = NHYP - 1; h >= 1; --h) {
        if (act) load12(ws + OFF_HMVT + (h - 1) * 144 + n * 12, rown);
        float v[R];
        lds12(Vmid[1], v);
        if (act) {
          float nx = row[0] + v[0];
          #pragma unroll
          for (int m = 1; m < R; ++m) nx = fmaxf(nx, row[m] + v[m]);
          ws[OFF_HSFX + (h - 1) * 12 + n] = nx;
          Vmid[1][n] = nx;
          #pragma unroll
          for (int m = 0; m < R; ++m) row[m] = rown[m];
        }
      }
    } else if (wid == 2) {
      // LSE forward -> nll
      float x = -3.0e38f;
      if (act) {
        x = trans[n * NTAGS + T_START] + ws[OFF_FEATS + n];
        Vmid[2][n] = x;
      }
      float row[R], rown[R];
      if (act) load12(ws + OFF_HMF + n * 12, row);
      for (int h = 0; h < NHYP; ++h) {
        if (act) load12(ws + OFF_HMF + (h + 1) * 144 + n * 12, rown); // h=7: SBV, unused
        float v[R];
        lds12(Vmid[2], v);
        if (act) {
          float tv[R]; float mx = -3.0e38f;
          #pragma unroll
          for (int m = 0; m < R; ++m) { tv[m] = row[m] + v[m]; mx = fmaxf(mx, tv[m]); }
          float sum = 0.f;
          #pragma unroll
          for (int m = 0; m < R; ++m) sum += __expf(tv[m] - mx);
          Vmid[2][n] = mx + __logf(sum);
          #pragma unroll
          for (int m = 0; m < R; ++m) row[m] = rown[m];
        }
      }
      if (lane == 0) {
        float v[R];
        lds12(Vmid[2], v);
        float mx = -3.0e38f;
        #pragma unroll
        for (int m = 0; m < R; ++m) mx = fmaxf(mx, v[m] + trans[T_STOP * NTAGS + m]);
        float sum = 0.f;
        #pragma unroll
        for (int m = 0; m < R; ++m) sum += __expf(v[m] + trans[T_STOP * NTAGS + m] - mx);
        out[0] = (mx + __logf(sum)) - ws[OFF_GOLD];
      }
    }
  }
  grid.sync();

  // ================= P4: expandA — hyper vectors -> super vectors ===========
  if (bid < 4 && tid < 64) {
    int q = tid >> 4;
    int g = tid & 15;
    int task = bid * 4 + q;
    int h = task >> 1;
    int dir = task & 1;
    bool act = (g < R);

    if (dir == 0) {
      float x = -3.0e38f;
      if (act) {
        x = ws[OFF_HBV + h * 12 + g];
        ws[OFF_SBV + (h * 16) * 12 + g] = x;
        VexA[q][g] = x;
      }
      float row[R], rown[R];
      if (act) load12(ws + OFF_SMV + (h * 16) * 144 + g * 12, row);
      for (int j = 0; j < 15; ++j) {
        int s = h * 16 + j;
        if (act) load12(ws + OFF_SMV + (s + 1) * 144 + g * 12, rown);
        float v[R];
        lds12(VexA[q], v);
        if (act) {
          float nx = row[0] + v[0];
          #pragma unroll
          for (int m = 1; m < R; ++m) nx = fmaxf(nx, row[m] + v[m]);
          ws[OFF_SBV + (s + 1) * 12 + g] = nx;
          VexA[q][g] = nx;
          #pragma unroll
          for (int m = 0; m < R; ++m) row[m] = rown[m];
        }
      }
    } else {
      float x = -3.0e38f;
      if (act) {
        x = ws[OFF_HSFX + h * 12 + g];
        ws[OFF_SSFX + (h * 16 + 15) * 12 + g] = x;
        VexA[q][g] = x;
      }
      float row[R], rown[R];
      if (act) load12(ws + OFF_SMVT + (h * 16 + 15) * 144 + g * 12, row);
      for (int j = 15; j >= 1; --j) {
        int s = h * 16 + j;
        if (act) load12(ws + OFF_SMVT + (s - 1) * 144 + g * 12, rown);
        float v[R];
        lds12(VexA[q], v);
        if (act) {
          float nx = row[0] + v[0];
          #pragma unroll
          for (int m = 1; m < R; ++m) nx = fmaxf(nx, row[m] + v[m]);
          ws[OFF_SSFX + (s - 1) * 12 + g] = nx;
          VexA[q][g] = nx;
          #pragma unroll
          for (int m = 0; m < R; ++m) row[m] = rown[m];
        }
      }
    }
  }
  grid.sync();

  // ================= P5: expandB — super vectors -> chunk vectors ===========
  if (bid < 64 && tid < 64) {
    int q = tid >> 4;
    int g = tid & 15;
    int task = bid * 4 + q;
    int s = task >> 1;
    int dir = task & 1;
    bool act = (g < R);

    if (dir == 0) {
      float x = -3.0e38f;
      if (act) {
        x = ws[OFF_SBV + s * 12 + g];
        ws[OFF_BV + (s * 16) * 12 + g] = x;
        VexB[q][g] = x;
      }
      float row[R], rown[R];
      if (act) load12(ws + OFF_PV + (s * 16) * 144 + g * 12, row);
      for (int j = 0; j < 15; ++j) {
        int c = s * 16 + j;
        if (act) load12(ws + OFF_PV + (c + 1) * 144 + g * 12, rown);
        float v[R];
        lds12(VexB[q], v);
        if (act) {
          float nx = row[0] + v[0];
          #pragma unroll
          for (int m = 1; m < R; ++m) nx = fmaxf(nx, row[m] + v[m]);
          ws[OFF_BV + (c + 1) * 12 + g] = nx;
          VexB[q][g] = nx;
          #pragma unroll
          for (int m = 0; m < R; ++m) row[m] = rown[m];
        }
      }
    } else {
      float x = -3.0e38f;
      if (act) {
        x = ws[OFF_SSFX + s * 12 + g];
        ws[OFF_SFX + (s * 16 + 15) * 12 + g] = x;
        VexB[q][g] = x;
      }
      float row[R], rown[R];
      if (act) load12(ws + OFF_PVC + (s * 16 + 15) * 144 + g * 12, row);
      for (int j = 15; j >= 1; --j) {
        int c = s * 16 + j;
        if (act) load12(ws + OFF_PVC + (c - 1) * 144 + g * 12, rown);
        float v[R];
        lds12(VexB[q], v);
        if (act) {
          float nx = row[0] + v[0];
          #pragma unroll
          for (int m = 1; m < R; ++m) nx = fmaxf(nx, row[m] + v[m]);
          ws[OFF_SFX + (c - 1) * 12 + g] = nx;
          VexB[q][g] = nx;
          #pragma unroll
          for (int m = 0; m < R; ++m) row[m] = rown[m];
        }
      }
    }
  }
  grid.sync();

  // ================= P6: decode — per-chunk re-scan + local backtrace =======
  {
    int q = tid >> 4;
    int g = tid & 15;
    if (q < 8) {
      int c = bid * 8 + q;
      int t0 = (c == 0) ? 1 : c * SCH;
      int t1 = c * SCH + SCH;
      bool act = (g < R);

      float treg[R];
      #pragma unroll
      for (int m = 0; m < R; ++m) treg[m] = act ? trans[g * NTAGS + m] : 0.f;

      float fv = act ? ws[OFF_BV + c * 12 + g] : -3.0e38f;
      Vdec[q][g] = fv;
      float fc = ws[OFF_FEATS + t0 * 12 + g];

      for (int t = t0; t < t1; ++t) {
        float fn = ws[OFF_FEATS + (t + 1) * 12 + g];   // off-end: EXPF, unused
        float v[R];
        lds12(Vdec[q], v);
        float best = -3.0e38f; int bi = 0;
        #pragma unroll
        for (int m = 0; m < R; ++m) {
          float cand = treg[m] + v[m];
          if (cand > best) { best = cand; bi = m; }
        }
        float nfv = best + fc;
        if (act) {
          bpd[q][t - t0][g] = (unsigned char)bi;
          Vdec[q][g] = nfv;
        }
        fc = fn;
      }

      Vdec[q][g] = act ? (Vdec[q][g] + ws[OFF_SFX + c * 12 + g]) : -3.0e38f;

      if (g == 0) {
        float best = Vdec[q][0]; int idx = 0;
        #pragma unroll
        for (int m = 1; m < R; ++m) {
          float v = Vdec[q][m];
          if (v > best) { best = v; idx = m; }
        }
        int cur = idx;
        int len = t1 - t0;
        out[2 + t0 + len - 1] = (float)cur;
        for (int tt = len - 1; tt >= 1; --tt) {
          cur = bpd[q][tt][cur];
          out[2 + t0 + tt - 1] = (float)cur;
        }
        if (c == 0) {
          cur = bpd[q][0][cur];
          out[2 + 0] = (float)cur;
        }
      }
    }
  }
}

// ======================= fallback path (original chain) =====================

__global__ __launch_bounds__(256) void k_goldsum(float* __restrict__ ws)
{
  __shared__ float gsh[256];
  float s = 0.f;
  for (int i = threadIdx.x; i < CCH; i += 256) s += ws[OFF_GOLDP + i];
  gsh[threadIdx.x] = s;
  __syncthreads();
  for (int off = 128; off > 0; off >>= 1) {
    if (threadIdx.x < off) gsh[threadIdx.x] += gsh[threadIdx.x + off];
    __syncthreads();
  }
  if (threadIdx.x == 0) ws[OFF_GOLD] = gsh[0];
}

__global__ __launch_bounds__(192) void k_fold(
    float* __restrict__ ws, int srcV, int srcF, int dstV, int dstVT, int dstF)
{
  __shared__ float Ml[144];
  __shared__ float Vl[144];
  int s   = blockIdx.x >> 1;
  int sem = blockIdx.x & 1;
  int l = threadIdx.x;
  bool act = (l < 144);
  int n = l / 12;
  int p = l - n * 12;
  int base = sem ? srcF : srcV;

  float V = (act && n == p) ? 0.f : -1.0e30f;
  float mreg = act ? ws[base + (s * 16) * 144 + l] : 0.f;

  for (int j = 0; j < 16; ++j) {
    if (act) { Ml[l] = mreg; Vl[l] = V; }
    __syncthreads();
    if (act) mreg = ws[base + (s * 16 + j + 1) * 144 + l];
    if (act) {
      if (sem == 0) {
        float best = -3.0e38f;
        #pragma unroll
        for (int m = 0; m < R; ++m)
          best = fmaxf(best, Ml[n * 12 + m] + Vl[m * 12 + p]);
        V = best;
      } else {
        float cand[R]; float mx = -3.0e38f;
        #pragma unroll
        for (int m = 0; m < R; ++m) {
          cand[m] = Ml[n * 12 + m] + Vl[m * 12 + p];
          mx = fmaxf(mx, cand[m]);
        }
        float sum = 0.f;
        #pragma unroll
        for (int m = 0; m < R; ++m) sum += __expf(cand[m] - mx);
        V = mx + __logf(sum);
      }
    }
    __syncthreads();
  }
  if (act) {
    if (sem == 0) {
      ws[dstV  + s * 144 + n * 12 + p] = V;
      ws[dstVT + s * 144 + p * 12 + n] = V;
    } else {
      ws[dstF + s * 144 + n * 12 + p] = V;
    }
  }
}

__global__ __launch_bounds__(192) void k_mid(
    const float* __restrict__ trans, float* __restrict__ ws,
    float* __restrict__ out)
{
  __shared__ float Vsh[3][16];
  int wid  = threadIdx.x >> 6;
  int lane = threadIdx.x & 63;
  int n = lane;
  bool act = (n < R);

  if (wid == 0) {
    float x = -3.0e38f;
    if (act) {
      x = trans[n * NTAGS + T_START] + ws[OFF_FEATS + n];
      ws[OFF_HBV + n] = x;
      Vsh[0][n] = x;
    }
    float row[R], rown[R];
    if (act) load12(ws + OFF_HMV + n * 12, row);
    for (int h = 0; h < NHYP; ++h) {
      if (act) load12(ws + OFF_HMV + (h + 1) * 144 + n * 12, rown);
      float v[R];
      lds12(Vsh[0], v);
      if (act) {
        float nx = row[0] + v[0];
        #pragma unroll
        for (int m = 1; m < R; ++m) nx = fmaxf(nx, row[m] + v[m]);
        if (h < NHYP - 1) ws[OFF_HBV + (h + 1) * 12 + n] = nx;
        Vsh[0][n] = nx;
        #pragma unroll
        for (int m = 0; m < R; ++m) row[m] = rown[m];
      }
    }
    if (lane == 0) {
      float v[R];
      lds12(Vsh[0], v);
      float ps = -3.0e38f;
      #pragma unroll
      for (int m = 0; m < R; ++m) ps = fmaxf(ps, v[m] + trans[T_STOP * NTAGS + m]);
      out[1] = ps;
    }
  } else if (wid == 1) {
    float x = -3.0e38f;
    if (act) {
      x = trans[T_STOP * NTAGS + n];
      ws[OFF_HSFX + (NHYP - 1) * 12 + n] = x;
      Vsh[1][n] = x;
    }
    float row[R], rown[R];
    if (act) load12(ws + OFF_HMVT + (NHYP - 1) * 144 + n * 12, row);
    for (int h = NHYP - 1; h >= 1; --h) {
      if (act) load12(ws + OFF_HMVT + (h - 1) * 144 + n * 12, rown);
      float v[R];
      lds12(Vsh[1], v);
      if (act) {
        float nx = row[0] + v[0];
        #pragma unroll
        for (int m = 1; m < R; ++m) nx = fmaxf(nx, row[m] + v[m]);
        ws[OFF_HSFX + (h - 1) * 12 + n] = nx;
        Vsh[1][n] = nx;
        #pragma unroll
        for (int m = 0; m < R; ++m) row[m] = rown[m];
      }
    }
  } else if (wid == 2) {
    float x = -3.0e38f;
    if (act) {
      x = trans[n * NTAGS + T_START] + ws[OFF_FEATS + n];
      Vsh[2][n] = x;
    }
    float row[R], rown[R];
    if (act) load12(ws + OFF_HMF + n * 12, row);
    for (int h = 0; h < NHYP; ++h) {
      if (act) load12(ws + OFF_HMF + (h + 1) * 144 + n * 12, rown);
      float v[R];
      lds12(Vsh[2], v);
      if (act) {
        float tv[R]; float mx = -3.0e38f;
        #pragma unroll
        for (int m = 0; m < R; ++m) { tv[m] = row[m] + v[m]; mx = fmaxf(mx, tv[m]); }
        float sum = 0.f;
        #pragma unroll
        for (int m = 0; m < R; ++m) sum += __expf(tv[m] - mx);
        Vsh[2][n] = mx + __logf(sum);
        #pragma unroll
        for (int m = 0; m < R; ++m) row[m] = rown[m];
      }
    }
    if (lane == 0) {
      float v[R];
      lds12(Vsh[2], v);
      float mx = -3.0e38f;
      #pragma unroll
      for (int m = 0; m < R; ++m) mx = fmaxf(mx, v[m] + trans[T_STOP * NTAGS + m]);
      float sum = 0.f;
      #pragma unroll
      for (int m = 0; m < R; ++m) sum += __expf(v[m] + trans[T_STOP * NTAGS + m] - mx);
      out[0] = (mx + __logf(sum)) - ws[OFF_GOLD];
    }
  }
}

__global__ __launch_bounds__(64) void k_expandA(
    float* __restrict__ ws)
{
  __shared__ float Vsh[4][16];
  int q = threadIdx.x >> 4;
  int g = threadIdx.x & 15;
  int task = blockIdx.x * 4 + q;
  int h = task >> 1;
  int dir = task & 1;
  bool act = (g < R);

  if (dir == 0) {
    float x = -3.0e38f;
    if (act) {
      x = ws[OFF_HBV + h * 12 + g];
      ws[OFF_SBV + (h * 16) * 12 + g] = x;
      Vsh[q][g] = x;
    }
    float row[R], rown[R];
    if (act) load12(ws + OFF_SMV + (h * 16) * 144 + g * 12, row);
    for (int j = 0; j < 15; ++j) {
      int s = h * 16 + j;
      if (act) load12(ws + OFF_SMV + (s + 1) * 144 + g * 12, rown);
      float v[R];
      lds12(Vsh[q], v);
      if (act) {
        float nx = row[0] + v[0];
        #pragma unroll
        for (int m = 1; m < R; ++m) nx = fmaxf(nx, row[m] + v[m]);
        ws[OFF_SBV + (s + 1) * 12 + g] = nx;
        Vsh[q][g] = nx;
        #pragma unroll
        for (int m = 0; m < R; ++m) row[m] = rown[m];
      }
    }
  } else {
    float x = -3.0e38f;
    if (act) {
      x = ws[OFF_HSFX + h * 12 + g];
      ws[OFF_SSFX + (h * 16 + 15) * 12 + g] = x;
      Vsh[q][g] = x;
    }
    float row[R], rown[R];
    if (act) load12(ws + OFF_SMVT + (h * 16 + 15) * 144 + g * 12, row);
    for (int j = 15; j >= 1; --j) {
      int s = h * 16 + j;
      if (act) load12(ws + OFF_SMVT + (s - 1) * 144 + g * 12, rown);
      float v[R];
      lds12(Vsh[q], v);
      if (act) {
        float nx = row[0] + v[0];
        #pragma unroll
        for (int m = 1; m < R; ++m) nx = fmaxf(nx, row[m] + v[m]);
        ws[OFF_SSFX + (s - 1) * 12 + g] = nx;
        Vsh[q][g] = nx;
        #pragma unroll
        for (int m = 0; m < R; ++m) row[m] = rown[m];
      }
    }
  }
}

__global__ __launch_bounds__(64) void k_expandB(
    float* __restrict__ ws)
{
  __shared__ float Vsh[4][16];
  int q = threadIdx.x >> 4;
  int g = threadIdx.x & 15;
  int task = blockIdx.x * 4 + q;
  int s = task >> 1;
  int dir = task & 1;
  bool act = (g < R);

  if (dir == 0) {
    float x = -3.0e38f;
    if (act) {
      x = ws[OFF_SBV + s * 12 + g];
      ws[OFF_BV + (s * 16) * 12 + g] = x;
      Vsh[q][g] = x;
    }
    float row[R], rown[R];
    if (act) load12(ws + OFF_PV + (s * 16) * 144 + g * 12, row);
    for (int j = 0; j < 15; ++j) {
      int c = s * 16 + j;
      if (act) load12(ws + OFF_PV + (c + 1) * 144 + g * 12, rown);
      float v[R];
      lds12(Vsh[q], v);
      if (act) {
        float nx = row[0] + v[0];
        #pragma unroll
        for (int m = 1; m < R; ++m) nx = fmaxf(nx, row[m] + v[m]);
        ws[OFF_BV + (c + 1) * 12 + g] = nx;
        Vsh[q][g] = nx;
        #pragma unroll
        for (int m = 0; m < R; ++m) row[m] = rown[m];
      }
    }
  } else {
    float x = -3.0e38f;
    if (act) {
      x = ws[OFF_SSFX + s * 12 + g];
      ws[OFF_SFX + (s * 16 + 15) * 12 + g] = x;
      Vsh[q][g] = x;
    }
    float row[R], rown[R];
    if (act) load12(ws + OFF_PVC + (s * 16 + 15) * 144 + g * 12, row);
    for (int j = 15; j >= 1; --j) {
      int c = s * 16 + j;
      if (act) load12(ws + OFF_PVC + (c - 1) * 144 + g * 12, rown);
      float v[R];
      lds12(Vsh[q], v);
      if (act) {
        float nx = row[0] + v[0];
        #pragma unroll
        for (int m = 1; m < R; ++m) nx = fmaxf(nx, row[m] + v[m]);
        ws[OFF_SFX + (c - 1) * 12 + g] = nx;
        Vsh[q][g] = nx;
        #pragma unroll
        for (int m = 0; m < R; ++m) row[m] = rown[m];
      }
    }
  }
}

__global__ __launch_bounds__(64) void k_decode(
    const float* __restrict__ trans, const float* __restrict__ ws,
    float* __restrict__ out)
{
  __shared__ unsigned char bp[4][SCH][16];
  __shared__ float Vsh[4][16];
  int q = threadIdx.x >> 4;
  int g = threadIdx.x & 15;
  int c = blockIdx.x * 4 + q;
  int t0 = (c == 0) ? 1 : c * SCH;
  int t1 = c * SCH + SCH;
  bool act = (g < R);

  float treg[R];
  #pragma unroll
  for (int m = 0; m < R; ++m) treg[m] = act ? trans[g * NTAGS + m] : 0.f;

  float fv = act ? ws[OFF_BV + c * 12 + g] : -3.0e38f;
  Vsh[q][g] = fv;
  float fc = ws[OFF_FEATS + t0 * 12 + g];

  for (int t = t0; t < t1; ++t) {
    float fn = ws[OFF_FEATS + (t + 1) * 12 + g];
    float v[R];
    lds12(Vsh[q], v);
    float best = -3.0e38f; int bi = 0;
    #pragma unroll
    for (int m = 0; m < R; ++m) {
      float cand = treg[m] + v[m];
      if (cand > best) { best = cand; bi = m; }
    }
    float nfv = best + fc;
    if (act) {
      bp[q][t - t0][g] = (unsigned char)bi;
      Vsh[q][g] = nfv;
    }
    fc = fn;
  }

  Vsh[q][g] = act ? (Vsh[q][g] + ws[OFF_SFX + c * 12 + g]) : -3.0e38f;

  if (g == 0) {
    float best = Vsh[q][0]; int idx = 0;
    #pragma unroll
    for (int m = 1; m < R; ++m) {
      float v = Vsh[q][m];
      if (v > best) { best = v; idx = m; }
    }
    int cur = idx;
    int len = t1 - t0;
    out[2 + t0 + len - 1] = (float)cur;
    for (int tt = len - 1; tt >= 1; --tt) {
      cur = bp[q][tt][cur];
      out[2 + t0 + tt - 1] = (float)cur;
    }
    if (c == 0) {
      cur = bp[q][0][cur];
      out[2 + 0] = (float)cur;
    }
  }
}

extern "C" void kernel_launch(void* const* d_in, const int* in_sizes, int n_in,
                              void* d_out, int out_size, void* d_ws, size_t ws_size,
                              hipStream_t stream) {
  (void)in_sizes; (void)n_in; (void)out_size; (void)ws_size;
  const int*   sentence = (const int*)d_in[0];
  const int*   tags     = (const int*)d_in[1];
  const float* emb      = (const float*)d_in[2];
  const float* W        = (const float*)d_in[3];
  const float* trans    = (const float*)d_in[4];
  float* ws  = (float*)d_ws;
  float* out = (float*)d_out;

  k_feats<<<LSEQ / 16, 256, 0, stream>>>(sentence, tags, emb, W, trans, ws);
  k_pass1<<<1024, 64, 0, stream>>>(trans, ws);

  void* kargs[] = { (void*)&trans, (void*)&ws, (void*)&out };
  hipError_t ce = hipLaunchCooperativeKernel((const void*)k_mega2, dim3(256),
                                             dim3(256), kargs, 0, stream);
  if (ce != hipSuccess) {
    // fallback: original tail chain (k_goldsum replaces the memset)
    k_goldsum<<<1, 256, 0, stream>>>(ws);
    k_fold<<<NSUP * 2, 192, 0, stream>>>(ws, OFF_PV, OFF_PF, OFF_SMV, OFF_SMVT, OFF_SMF);
    k_fold<<<NHYP * 2, 192, 0, stream>>>(ws, OFF_SMV, OFF_SMF, OFF_HMV, OFF_HMVT, OFF_HMF);
    k_mid<<<1, 192, 0, stream>>>(trans, ws, out);
    k_expandA<<<4, 64, 0, stream>>>(ws);
    k_expandB<<<64, 64, 0, stream>>>(ws);
    k_decode<<<CCH / 4, 64, 0, stream>>>(trans, ws, out);
  }
}

// Round 3
// 244.387 us; speedup vs baseline: 1.7601x; 1.6253x over previous
//
#include <hip/hip_runtime.h>

// EmbeddingCRF: feats = emb[sentence] @ W^T; CRF forward (LSE), gold score,
// Viterbi decode. Parallel-in-time via 12x12 semiring transfer matrices.
// R4: 4-level scan tree — 2048 chunks(16) -> 128 supers -> 8 hypers -> seq 8.
// R7: grid.sync() measured ~31us each on MI355X (R6: 5 syncs = 155us of
// k_mega2's 170us) — cooperative fusion abandoned. Ordinary dispatches are
// the cheap barrier (~5us). Instead: minimize dispatch COUNT by fusing only
// block-local work: fold2+gold+mid+expandA -> k_midexpA (1 block, LDS
// hand-off); expandB+decode -> k_expBdec (per-super block, BV/SFX in LDS,
// no global round-trip); folds stage all 16 matrices in one LDS burst (one
// exposed latency instead of 16). 10 dispatches (R4) -> 6, no memset.

#define LSEQ    32768
#define NTAGS   14
#define R       12
#define T_START 12
#define T_STOP  13
#define EMBD    300
#define CCH     2048  // chunks
#define SCH     16    // steps per chunk
#define NSUP    128   // supers (16 chunks each)
#define NHYP    8     // hypers (16 supers each)

// ws layout (float offsets)
#define OFF_FEATS 0         // [L][12]
#define OFF_EXPF  393216    // [L][12]
#define OFF_FMAX  786432    // [L]
#define OFF_PF    819200    // [2048][n][p] LSE chunk mats (log domain)
#define OFF_PV    1114112   // [2048][n][p] max-plus chunk mats
#define OFF_PVC   1409024   // [2048][p][n] transposed
#define OFF_BV    1703936   // [2048][12] (unused since R7; kept for layout)
#define OFF_SFX   1728512   // [2048][12] (unused since R7; kept for layout)
#define OFF_GOLD  1753088   // [1] (unused since R7)
#define OFF_SMV   1753104   // [128][n][p]
#define OFF_SMVT  1771536   // [128][p][n]
#define OFF_SMF   1789968   // [128][n][p]
#define OFF_HMV   1808400   // [8][n][p]
#define OFF_HMVT  1809552   // [8][p][n]
#define OFF_HMF   1810704   // [8][n][p]
#define OFF_SBV   1811856   // [128][12]
#define OFF_SSFX  1813392   // [128][12]
#define OFF_HBV   1814928   // [8][12] (unused since R7; LDS hand-off)
#define OFF_HSFX  1815024   // [8][12] (unused since R7; LDS hand-off)
#define OFF_GOLDP 1815120   // [2048] per-block gold partials

__device__ __forceinline__ void load12(const float* __restrict__ p, float* r) {
  const float4* p4 = (const float4*)p;
  float4 a = p4[0], b = p4[1], c = p4[2];
  r[0]=a.x; r[1]=a.y; r[2]=a.z; r[3]=a.w;
  r[4]=b.x; r[5]=b.y; r[6]=b.z; r[7]=b.w;
  r[8]=c.x; r[9]=c.y; r[10]=c.z; r[11]=c.w;
}

__device__ __forceinline__ void lds12(const float* p, float* r) {
  const float4* p4 = (const float4*)p;
  float4 a = p4[0], b = p4[1], c = p4[2];
  r[0]=a.x; r[1]=a.y; r[2]=a.z; r[3]=a.w;
  r[4]=b.x; r[5]=b.y; r[6]=b.z; r[7]=b.w;
  r[8]=c.x; r[9]=c.y; r[10]=c.z; r[11]=c.w;
}

// ---------------- K1: feats + expfeat + featmax + gold partials -------------
__global__ __launch_bounds__(256) void k_feats(
    const int* __restrict__ sentence, const int* __restrict__ tags,
    const float* __restrict__ emb, const float* __restrict__ W,
    const float* __restrict__ trans, float* __restrict__ ws)
{
  __shared__ float Wl[NTAGS * EMBD];
  __shared__ float gacc;
  for (int i = threadIdx.x; i < NTAGS * EMBD; i += 256) Wl[i] = W[i];
  if (threadIdx.x == 0) gacc = 0.f;
  __syncthreads();

  int grp = threadIdx.x >> 4;
  int g   = threadIdx.x & 15;
  int pos = blockIdx.x * 16 + grp;
  int row = sentence[pos];

  float acc = 0.f;
  if (g < R) {
    const float4* e4 = (const float4*)(emb + (size_t)row * EMBD);
    const float4* w4 = (const float4*)(Wl + g * EMBD);
    #pragma unroll 5
    for (int i = 0; i < EMBD / 4; ++i) {
      float4 a = e4[i]; float4 b = w4[i];
      acc += a.x*b.x + a.y*b.y + a.z*b.z + a.w*b.w;
    }
  }
  float feat = (g < R) ? acc : -3.0e38f;
  float mx = feat;
  #pragma unroll
  for (int off = 1; off < 16; off <<= 1)
    mx = fmaxf(mx, __shfl_xor(mx, off, 16));

  if (g < R) {
    ws[OFF_FEATS + pos * 12 + g] = feat;
    ws[OFF_EXPF  + pos * 12 + g] = __expf(feat - mx);
  }
  if (g == 0) ws[OFF_FMAX + pos] = mx;

  int tg = tags[pos];
  if (g == tg) {
    int prev = (pos == 0) ? T_START : tags[pos - 1];
    float gc = feat + trans[tg * NTAGS + prev];
    if (pos == LSEQ - 1) gc += trans[T_STOP * NTAGS + tg];
    atomicAdd(&gacc, gc);
  }
  __syncthreads();
  if (threadIdx.x == 0) ws[OFF_GOLDP + blockIdx.x] = gacc;
}

// ---------------- K2: chunk transfer matrices (own register budget) ---------
// 1024 blocks x 64 thr: blocks 0..511 LSE, 512..1023 viterbi; 4 chunks/block.
__global__ __launch_bounds__(64) void k_pass1(
    const float* __restrict__ trans, float* __restrict__ ws)
{
  int role = blockIdx.x >> 9;
  int q = threadIdx.x >> 4;
  int p = threadIdx.x & 15;
  int c = (blockIdx.x & 511) * 4 + q;
  int t0 = (c == 0) ? 1 : c * SCH;
  int t1 = c * SCH + SCH;
  bool act = (p < R);

  float Treg[R][R];

  if (role == 0) {
    #pragma unroll
    for (int n = 0; n < R; ++n)
      #pragma unroll
      for (int m = 0; m < R; ++m)
        Treg[n][m] = __expf(trans[n * NTAGS + m]);

    float E[R];
    #pragma unroll
    for (int m = 0; m < R; ++m) E[m] = (m == p) ? 1.f : 0.f;
    int kacc = 0;
    float sfeat = 0.f;

    float ef[R];
    load12(ws + OFF_EXPF + t0 * 12, ef);
    float fm = ws[OFF_FMAX + t0];

    for (int t = t0; t < t1; ++t) {
      float efn[R];
      load12(ws + OFF_EXPF + (t + 1) * 12, efn);   // off-end lands in FMAX: safe
      float fmn = ws[OFF_FMAX + t + 1];            // off-end lands in PF: safe
      sfeat += fm;
      float NE[R];
      #pragma unroll
      for (int n = 0; n < R; ++n) {
        float s = Treg[n][0] * E[0];
        #pragma unroll
        for (int m = 1; m < R; ++m) s = fmaf(Treg[n][m], E[m], s);
        NE[n] = s * ef[n];
      }
      #pragma unroll
      for (int n = 0; n < R; ++n) E[n] = NE[n];
      if ((t & 7) == 7) {
        float mx = E[0];
        #pragma unroll
        for (int n = 1; n < R; ++n) mx = fmaxf(mx, E[n]);
        if (mx > 0.f) {
          int k = ((__float_as_int(mx) >> 23) & 0xFF) - 127;
          float sc = __int_as_float((127 - k) << 23);
          #pragma unroll
          for (int n = 0; n < R; ++n) E[n] *= sc;
          kacc += k;
        }
      }
      #pragma unroll
      for (int n = 0; n < R; ++n) ef[n] = efn[n];
      fm = fmn;
    }
    if (act) {
      float base = (float)kacc * 0.6931471805599453f + sfeat;
      #pragma unroll
      for (int n = 0; n < R; ++n) {
        float v = (E[n] > 0.f) ? (__logf(E[n]) + base) : -1.0e30f;
        ws[OFF_PF + c * 144 + n * 12 + p] = v;
      }
    }
  } else {
    #pragma unroll
    for (int n = 0; n < R; ++n)
      #pragma unroll
      for (int m = 0; m < R; ++m)
        Treg[n][m] = trans[n * NTAGS + m];

    float V[R];
    #pragma unroll
    for (int m = 0; m < R; ++m) V[m] = (m == p) ? 0.f : -1.0e30f;

    float fr[R];
    load12(ws + OFF_FEATS + t0 * 12, fr);

    for (int t = t0; t < t1; ++t) {
      float frn[R];
      load12(ws + OFF_FEATS + (t + 1) * 12, frn);  // off-end lands in EXPF: safe
      float NV[R];
      #pragma unroll
      for (int n = 0; n < R; ++n) {
        float b = Treg[n][0] + V[0];
        #pragma unroll
        for (int m = 1; m < R; ++m) b = fmaxf(b, Treg[n][m] + V[m]);
        NV[n] = b + fr[n];
      }
      #pragma unroll
      for (int n = 0; n < R; ++n) { V[n] = NV[n]; fr[n] = frn[n]; }
    }
    if (act) {
      #pragma unroll
      for (int n = 0; n < R; ++n) {
        ws[OFF_PV  + c * 144 + n * 12 + p] = V[n];
        ws[OFF_PVC + c * 144 + p * 12 + n] = V[n];
      }
    }
  }
}

// ---------------- K_foldS: 16-way semiring fold, LDS-staged matrices --------
// grid = Nout*2; blockIdx&1: 0 = viterbi (srcV -> dstV+dstVT), 1 = LSE.
// All 16 source matrices staged to LDS in one burst (one exposed latency).
__global__ __launch_bounds__(192) void k_foldS(
    float* __restrict__ ws, int srcV, int srcF, int dstV, int dstVT, int dstF)
{
  __shared__ float Msh[16 * 144];   // 9.2 KB
  __shared__ float Vl[144];
  int s   = blockIdx.x >> 1;
  int sem = blockIdx.x & 1;
  int l = threadIdx.x;
  bool act = (l < 144);
  int n = l / 12;
  int p = l - n * 12;
  int base = sem ? srcF : srcV;

  // stage 16 mats = 2304 floats = 576 float4; 192 thr x 3
  const float4* src4 = (const float4*)(ws + base + s * (16 * 144));
  float4* d4 = (float4*)Msh;
  #pragma unroll
  for (int i = 0; i < 3; ++i) d4[l + i * 192] = src4[l + i * 192];

  float V = (act && n == p) ? 0.f : -1.0e30f;
  __syncthreads();

  for (int j = 0; j < 16; ++j) {
    if (act) Vl[l] = V;
    __syncthreads();
    if (act) {
      const float* M = Msh + j * 144 + n * 12;
      if (sem == 0) {
        float best = -3.0e38f;
        #pragma unroll
        for (int m = 0; m < R; ++m)
          best = fmaxf(best, M[m] + Vl[m * 12 + p]);
        V = best;
      } else {
        float cand[R]; float mx = -3.0e38f;
        #pragma unroll
        for (int m = 0; m < R; ++m) {
          cand[m] = M[m] + Vl[m * 12 + p];
          mx = fmaxf(mx, cand[m]);
        }
        float sum = 0.f;
        #pragma unroll
        for (int m = 0; m < R; ++m) sum += __expf(cand[m] - mx);
        V = mx + __logf(sum);
      }
    }
    __syncthreads();
  }
  if (act) {
    if (sem == 0) {
      ws[dstV  + s * 144 + n * 12 + p] = V;
      ws[dstVT + s * 144 + p * 12 + n] = V;
    } else {
      ws[dstF + s * 144 + n * 12 + p] = V;
    }
  }
}

// ---------------- K_midexpA: gold + hyper scans + expandA (1 block) ---------
// waves 0-2: mid scans (Viterbi fwd / Viterbi sfx / LSE fwd); wave 3: gold
// reduce. __syncthreads. out[0]; expandA: 16 tasks x 16 lanes (tid<128 dir0,
// tid>=128 dir1 — no intra-wave divergence). HBV/HSFX via LDS.
__global__ __launch_bounds__(256) void k_midexpA(
    const float* __restrict__ trans, float* __restrict__ ws,
    float* __restrict__ out)
{
  __shared__ float hbv_sh[NHYP][12];
  __shared__ float hsfx_sh[NHYP][12];
  __shared__ float Vm[3][16];
  __shared__ float VexA[16][16];
  __shared__ float gold_sh, lse_sh;

  int tid  = threadIdx.x;
  int wid  = tid >> 6;
  int lane = tid & 63;

  if (wid == 0) {
    // Viterbi forward -> hbv_sh + path_score
    int n = lane; bool act = (n < R);
    float x = -3.0e38f;
    if (act) {
      x = trans[n * NTAGS + T_START] + ws[OFF_FEATS + n];
      hbv_sh[0][n] = x;
      Vm[0][n] = x;
    }
    float row[R], rown[R];
    if (act) load12(ws + OFF_HMV + n * 12, row);
    for (int h = 0; h < NHYP; ++h) {
      if (act) load12(ws + OFF_HMV + (h + 1) * 144 + n * 12, rown); // h=7: HMVT, unused
      float v[R];
      lds12(Vm[0], v);
      if (act) {
        float nx = row[0] + v[0];
        #pragma unroll
        for (int m = 1; m < R; ++m) nx = fmaxf(nx, row[m] + v[m]);
        if (h < NHYP - 1) hbv_sh[h + 1][n] = nx;
        Vm[0][n] = nx;
        #pragma unroll
        for (int m = 0; m < R; ++m) row[m] = rown[m];
      }
    }
    if (lane == 0) {
      float v[R];
      lds12(Vm[0], v);
      float ps = -3.0e38f;
      #pragma unroll
      for (int m = 0; m < R; ++m) ps = fmaxf(ps, v[m] + trans[T_STOP * NTAGS + m]);
      out[1] = ps;
    }
  } else if (wid == 1) {
    // Viterbi suffix -> hsfx_sh
    int n = lane; bool act = (n < R);
    float x = -3.0e38f;
    if (act) {
      x = trans[T_STOP * NTAGS + n];
      hsfx_sh[NHYP - 1][n] = x;
      Vm[1][n] = x;
    }
    float row[R], rown[R];
    if (act) load12(ws + OFF_HMVT + (NHYP - 1) * 144 + n * 12, row);
    for (int h = NHYP - 1; h >= 1; --h) {
      if (act) load12(ws + OFF_HMVT + (h - 1) * 144 + n * 12, rown);
      float v[R];
      lds12(Vm[1], v);
      if (act) {
        float nx = row[0] + v[0];
        #pragma unroll
        for (int m = 1; m < R; ++m) nx = fmaxf(nx, row[m] + v[m]);
        hsfx_sh[h - 1][n] = nx;
        Vm[1][n] = nx;
        #pragma unroll
        for (int m = 0; m < R; ++m) row[m] = rown[m];
      }
    }
  } else if (wid == 2) {
    // LSE forward -> lse_sh
    int n = lane; bool act = (n < R);
    float x = -3.0e38f;
    if (act) {
      x = trans[n * NTAGS + T_START] + ws[OFF_FEATS + n];
      Vm[2][n] = x;
    }
    float row[R], rown[R];
    if (act) load12(ws + OFF_HMF + n * 12, row);
    for (int h = 0; h < NHYP; ++h) {
      if (act) load12(ws + OFF_HMF + (h + 1) * 144 + n * 12, rown); // h=7: SBV, unused
      float v[R];
      lds12(Vm[2], v);
      if (act) {
        float tv[R]; float mx = -3.0e38f;
        #pragma unroll
        for (int m = 0; m < R; ++m) { tv[m] = row[m] + v[m]; mx = fmaxf(mx, tv[m]); }
        float sum = 0.f;
        #pragma unroll
        for (int m = 0; m < R; ++m) sum += __expf(tv[m] - mx);
        Vm[2][n] = mx + __logf(sum);
        #pragma unroll
        for (int m = 0; m < R; ++m) row[m] = rown[m];
      }
    }
    if (lane == 0) {
      float v[R];
      lds12(Vm[2], v);
      float mx = -3.0e38f;
      #pragma unroll
      for (int m = 0; m < R; ++m) mx = fmaxf(mx, v[m] + trans[T_STOP * NTAGS + m]);
      float sum = 0.f;
      #pragma unroll
      for (int m = 0; m < R; ++m) sum += __expf(v[m] + trans[T_STOP * NTAGS + m] - mx);
      lse_sh = mx + __logf(sum);
    }
  } else {
    // gold reduce over 2048 partials
    float s = 0.f;
    for (int i = lane; i < CCH; i += 64) s += ws[OFF_GOLDP + i];
    #pragma unroll
    for (int off = 32; off > 0; off >>= 1) s += __shfl_xor(s, off);
    if (lane == 0) gold_sh = s;
  }
  __syncthreads();

  if (tid == 0) out[0] = lse_sh - gold_sh;

  // expandA: hyper vectors -> super vectors (SBV/SSFX to ws for k_expBdec)
  {
    int dir  = tid >> 7;          // waves 0-1: dir0, waves 2-3: dir1
    int h    = (tid >> 4) & 7;
    int g    = tid & 15;
    int task = tid >> 4;
    bool act = (g < R);

    if (dir == 0) {
      float x = -3.0e38f;
      if (act) {
        x = hbv_sh[h][g];
        ws[OFF_SBV + (h * 16) * 12 + g] = x;
        VexA[task][g] = x;
      }
      float row[R], rown[R];
      if (act) load12(ws + OFF_SMV + (h * 16) * 144 + g * 12, row);
      for (int j = 0; j < 15; ++j) {
        int s = h * 16 + j;
        if (act) load12(ws + OFF_SMV + (s + 1) * 144 + g * 12, rown);
        float v[R];
        lds12(VexA[task], v);
        if (act) {
          float nx = row[0] + v[0];
          #pragma unroll
          for (int m = 1; m < R; ++m) nx = fmaxf(nx, row[m] + v[m]);
          ws[OFF_SBV + (s + 1) * 12 + g] = nx;
          VexA[task][g] = nx;
          #pragma unroll
          for (int m = 0; m < R; ++m) row[m] = rown[m];
        }
      }
    } else {
      float x = -3.0e38f;
      if (act) {
        x = hsfx_sh[h][g];
        ws[OFF_SSFX + (h * 16 + 15) * 12 + g] = x;
        VexA[task][g] = x;
      }
      float row[R], rown[R];
      if (act) load12(ws + OFF_SMVT + (h * 16 + 15) * 144 + g * 12, row);
      for (int j = 15; j >= 1; --j) {
        int s = h * 16 + j;
        if (act) load12(ws + OFF_SMVT + (s - 1) * 144 + g * 12, rown);
        float v[R];
        lds12(VexA[task], v);
        if (act) {
          float nx = row[0] + v[0];
          #pragma unroll
          for (int m = 1; m < R; ++m) nx = fmaxf(nx, row[m] + v[m]);
          ws[OFF_SSFX + (s - 1) * 12 + g] = nx;
          VexA[task][g] = nx;
          #pragma unroll
          for (int m = 0; m < R; ++m) row[m] = rown[m];
        }
      }
    }
  }
}

// ---------------- K_expBdec: per-super expandB scans + decode ---------------
// 128 blocks x 256 thr. Phase A: wave0 lanes 0-15 compute BV for the super's
// 16 chunks (LDS); wave1 lanes 0-15 compute SFX. Phase B: decode 16 chunks
// x 16 lanes. No BV/SFX global round-trip.
__global__ __launch_bounds__(256) void k_expBdec(
    const float* __restrict__ trans, const float* __restrict__ ws,
    float* __restrict__ out)
{
  __shared__ float bv_sh[SCH][12];
  __shared__ float sfx_sh[SCH][12];
  __shared__ float Vdec[SCH][16];
  __shared__ unsigned char bpd[SCH][SCH][16];

  int tid = threadIdx.x;
  int s   = blockIdx.x;

  if (tid < 16) {
    // dir0: BV scan over PV mats
    int g = tid; bool act = (g < R);
    float x = -3.0e38f;
    if (act) { x = ws[OFF_SBV + s * 12 + g]; bv_sh[0][g] = x; }
    float row[R], rown[R];
    if (act) load12(ws + OFF_PV + (s * 16) * 144 + g * 12, row);
    for (int j = 0; j < 15; ++j) {
      if (act) load12(ws + OFF_PV + (s * 16 + j + 1) * 144 + g * 12, rown);
      float v[R];
      lds12(bv_sh[j], v);
      if (act) {
        float nx = row[0] + v[0];
        #pragma unroll
        for (int m = 1; m < R; ++m) nx = fmaxf(nx, row[m] + v[m]);
        bv_sh[j + 1][g] = nx;
        #pragma unroll
        for (int m = 0; m < R; ++m) row[m] = rown[m];
      }
    }
  } else if (tid >= 64 && tid < 80) {
    // dir1: SFX scan over PVC mats
    int g = tid - 64; bool act = (g < R);
    float x = -3.0e38f;
    if (act) { x = ws[OFF_SSFX + s * 12 + g]; sfx_sh[SCH - 1][g] = x; }
    float row[R], rown[R];
    if (act) load12(ws + OFF_PVC + (s * 16 + 15) * 144 + g * 12, row);
    for (int j = 15; j >= 1; --j) {
      if (act) load12(ws + OFF_PVC + (s * 16 + j - 1) * 144 + g * 12, rown);
      float v[R];
      lds12(sfx_sh[j], v);
      if (act) {
        float nx = row[0] + v[0];
        #pragma unroll
        for (int m = 1; m < R; ++m) nx = fmaxf(nx, row[m] + v[m]);
        sfx_sh[j - 1][g] = nx;
        #pragma unroll
        for (int m = 0; m < R; ++m) row[m] = rown[m];
      }
    }
  }
  __syncthreads();

  // decode: 16 chunks x 16 lanes
  {
    int q = tid >> 4;
    int g = tid & 15;
    int c = s * 16 + q;
    int t0 = (c == 0) ? 1 : c * SCH;
    int t1 = c * SCH + SCH;
    bool act = (g < R);

    float treg[R];
    #pragma unroll
    for (int m = 0; m < R; ++m) treg[m] = act ? trans[g * NTAGS + m] : 0.f;

    float fv = act ? bv_sh[q][g] : -3.0e38f;
    Vdec[q][g] = fv;
    float fc = ws[OFF_FEATS + t0 * 12 + g];

    for (int t = t0; t < t1; ++t) {
      float fn = ws[OFF_FEATS + (t + 1) * 12 + g];   // off-end: EXPF, unused
      float v[R];
      lds12(Vdec[q], v);
      float best = -3.0e38f; int bi = 0;
      #pragma unroll
      for (int m = 0; m < R; ++m) {
        float cand = treg[m] + v[m];
        if (cand > best) { best = cand; bi = m; }
      }
      float nfv = best + fc;
      if (act) {
        bpd[q][t - t0][g] = (unsigned char)bi;
        Vdec[q][g] = nfv;
      }
      fc = fn;
    }

    Vdec[q][g] = act ? (Vdec[q][g] + sfx_sh[q][g]) : -3.0e38f;

    if (g == 0) {
      float best = Vdec[q][0]; int idx = 0;
      #pragma unroll
      for (int m = 1; m < R; ++m) {
        float v = Vdec[q][m];
        if (v > best) { best = v; idx = m; }
      }
      int cur = idx;
      int len = t1 - t0;
      out[2 + t0 + len - 1] = (float)cur;
      for (int tt = len - 1; tt >= 1; --tt) {
        cur = bpd[q][tt][cur];
        out[2 + t0 + tt - 1] = (float)cur;
      }
      if (c == 0) {
        cur = bpd[q][0][cur];
        out[2 + 0] = (float)cur;
      }
    }
  }
}

extern "C" void kernel_launch(void* const* d_in, const int* in_sizes, int n_in,
                              void* d_out, int out_size, void* d_ws, size_t ws_size,
                              hipStream_t stream) {
  (void)in_sizes; (void)n_in; (void)out_size; (void)ws_size;
  const int*   sentence = (const int*)d_in[0];
  const int*   tags     = (const int*)d_in[1];
  const float* emb      = (const float*)d_in[2];
  const float* W        = (const float*)d_in[3];
  const float* trans    = (const float*)d_in[4];
  float* ws  = (float*)d_ws;
  float* out = (float*)d_out;

  k_feats<<<LSEQ / 16, 256, 0, stream>>>(sentence, tags, emb, W, trans, ws);
  k_pass1<<<1024, 64, 0, stream>>>(trans, ws);
  k_foldS<<<NSUP * 2, 192, 0, stream>>>(ws, OFF_PV, OFF_PF, OFF_SMV, OFF_SMVT, OFF_SMF);
  k_foldS<<<NHYP * 2, 192, 0, stream>>>(ws, OFF_SMV, OFF_SMF, OFF_HMV, OFF_HMVT, OFF_HMF);
  k_midexpA<<<1, 256, 0, stream>>>(trans, ws, out);
  k_expBdec<<<NSUP, 256, 0, stream>>>(trans, ws, out);
}